// Round 1
// baseline (2731.205 us; speedup 1.0000x reference)
//
#include <hip/hip_runtime.h>

#define N_NODES 100000
#define N_EDGES 1600000
#define D 128
#define DE 16
#define G 512
#define EPSBN 1e-5f

// ---------------- K0: init deg=1 (self loop), zero counters/accumulators ----------------
__global__ void k_init(int* __restrict__ deg, int* __restrict__ ecnt,
                       float* __restrict__ gcnt, float* __restrict__ gsum) {
  int i = blockIdx.x * 256 + threadIdx.x;
  if (i < N_NODES) deg[i] = 1;
  if (i < G) { ecnt[i] = 0; gcnt[i] = 0.f; }
  if (i < G * D) gsum[i] = 0.f;
}

// ---------------- K1: count in-degree per node + edges per graph (LDS bins) ----------------
__global__ void k_count(const int* __restrict__ ei, const int* __restrict__ batch,
                        int* __restrict__ deg, int* __restrict__ ecnt) {
  __shared__ int bins[G];
  int tid = threadIdx.x;
  for (int i = tid; i < G; i += 256) bins[i] = 0;
  __syncthreads();
  int base = blockIdx.x * 4096;
  for (int t = tid; t < 4096; t += 256) {
    int e = base + t;
    if (e < N_EDGES) {
      int s = ei[e];
      int d = ei[N_EDGES + e];
      atomicAdd(&deg[d], 1);
      atomicAdd(&bins[batch[s]], 1);
    }
  }
  __syncthreads();
  for (int i = tid; i < G; i += 256) if (bins[i]) atomicAdd(&ecnt[i], bins[i]);
}

// ---------------- K2: single-block exclusive scans (node CSR starts + graph bucket starts) ----
__global__ void k_scan(const int* __restrict__ deg, int* __restrict__ rs, int* __restrict__ cursor,
                       const int* __restrict__ ecnt, int* __restrict__ ebs, int* __restrict__ ecur) {
  __shared__ int sb[1024];
  int tid = threadIdx.x;
  const int chunk = (N_NODES + 1023) / 1024;  // 98
  int start = tid * chunk;
  int end = start + chunk; if (end > N_NODES) end = N_NODES;
  int s = 0;
  for (int i = start; i < end; ++i) s += deg[i];
  sb[tid] = s;
  __syncthreads();
  for (int off = 1; off < 1024; off <<= 1) {
    int t = (tid >= off) ? sb[tid - off] : 0;
    __syncthreads();
    sb[tid] += t;
    __syncthreads();
  }
  int run = sb[tid] - s;  // exclusive prefix of this chunk
  for (int i = start; i < end; ++i) { rs[i] = run; cursor[i] = run; run += deg[i]; }
  __syncthreads();
  int v2 = (tid < G) ? ecnt[tid] : 0;
  sb[tid] = v2;
  __syncthreads();
  for (int off = 1; off < 1024; off <<= 1) {
    int t = (tid >= off) ? sb[tid - off] : 0;
    __syncthreads();
    sb[tid] += t;
    __syncthreads();
  }
  if (tid < G) { ebs[tid] = sb[tid] - v2; ecur[tid] = sb[tid] - v2; }
}

// ---------------- K3: dinv = rsqrt(deg) ----------------
__global__ void k_dinv(const int* __restrict__ deg, float* __restrict__ dinv) {
  int i = blockIdx.x * 256 + threadIdx.x;
  if (i < N_NODES) dinv[i] = rsqrtf((float)deg[i]);
}

// ---------------- K4: scatter edges into node-CSR and graph buckets ----------------
__global__ void k_scatter(const int* __restrict__ ei, const int* __restrict__ batch,
                          int* __restrict__ cursor, int* __restrict__ ecur,
                          int* __restrict__ nbr, int* __restrict__ ebkt) {
  int e = blockIdx.x * 256 + threadIdx.x;
  if (e >= N_EDGES) return;
  int s = ei[e], d = ei[N_EDGES + e];
  int pos = atomicAdd(&cursor[d], 1);
  nbr[pos] = s;
  int ep = atomicAdd(&ecur[batch[s]], 1);
  ebkt[ep] = e;
}

// ---------------- K5/K7: out = (X @ W) * dinv[row]   (N x 128 @ 128 x 128, fp32) -------------
__global__ __launch_bounds__(256) void k_gemm_scale(const float* __restrict__ X,
                                                    const float* __restrict__ W,
                                                    const float* __restrict__ dinv,
                                                    float* __restrict__ out) {
  __shared__ float sX[128][32];
  __shared__ float sW[32][128];
  int tid = threadIdx.x;
  int tx = tid & 15, ty = tid >> 4;
  int rowBase = blockIdx.x * 128;
  float acc[8][8] = {};
  for (int kc = 0; kc < 128; kc += 32) {
    #pragma unroll
    for (int i = 0; i < 4; ++i) {
      int idx = tid + i * 256;          // 0..1023 -> 128 rows x 8 float4
      int r = idx >> 3, kq = idx & 7;
      int row = rowBase + r;
      float4 v = make_float4(0.f, 0.f, 0.f, 0.f);
      if (row < N_NODES) v = *(const float4*)(X + (size_t)row * 128 + kc + kq * 4);
      *(float4*)(&sX[r][kq * 4]) = v;
    }
    #pragma unroll
    for (int i = 0; i < 4; ++i) {
      int idx = tid + i * 256;          // 32 rows x 32 float4
      int k = idx >> 5, cq = idx & 31;
      *(float4*)(&sW[k][cq * 4]) = *(const float4*)(W + (size_t)(kc + k) * 128 + cq * 4);
    }
    __syncthreads();
    #pragma unroll 4
    for (int k = 0; k < 32; ++k) {
      float a[8], b[8];
      #pragma unroll
      for (int j = 0; j < 8; ++j) a[j] = sX[ty * 8 + j][k];
      *(float4*)(&b[0]) = *(float4*)(&sW[k][tx * 8]);
      *(float4*)(&b[4]) = *(float4*)(&sW[k][tx * 8 + 4]);
      #pragma unroll
      for (int j = 0; j < 8; ++j)
        #pragma unroll
        for (int c = 0; c < 8; ++c) acc[j][c] += a[j] * b[c];
    }
    __syncthreads();
  }
  #pragma unroll
  for (int j = 0; j < 8; ++j) {
    int row = rowBase + ty * 8 + j;
    if (row < N_NODES) {
      float dv = dinv[row];
      float4 o0, o1;
      o0.x = acc[j][0] * dv; o0.y = acc[j][1] * dv; o0.z = acc[j][2] * dv; o0.w = acc[j][3] * dv;
      o1.x = acc[j][4] * dv; o1.y = acc[j][5] * dv; o1.z = acc[j][6] * dv; o1.w = acc[j][7] * dv;
      *(float4*)(out + (size_t)row * 128 + tx * 8) = o0;
      *(float4*)(out + (size_t)row * 128 + tx * 8 + 4) = o1;
    }
  }
}

// ---------------- K6: CSR aggregate + bias + BN + ReLU -> out ----------------
__global__ void k_agg_bn(const float* __restrict__ A, const int* __restrict__ nbr,
                         const int* __restrict__ rs, const int* __restrict__ deg,
                         const float* __restrict__ dinv,
                         const float* __restrict__ b, const float* __restrict__ gm,
                         const float* __restrict__ bt, const float* __restrict__ m,
                         const float* __restrict__ v, float* __restrict__ out) {
  int tid = threadIdx.x;
  int c = tid & 127;
  int half = tid >> 7;
  int gid = blockIdx.x * 2 + half;  // 32 nodes per group
  if (gid * 32 >= N_NODES) return;
  float scale = gm[c] * rsqrtf(v[c] + EPSBN);
  float shift = bt[c] - m[c] * scale;
  float bias = b[c];
  int base = gid * 32;
  for (int nn = 0; nn < 32; ++nn) {
    int i = base + nn;
    float sum = A[(size_t)i * 128 + c];   // self loop (already dinv-scaled)
    int j = rs[i];
    int end = j + deg[i] - 1;             // indeg real edges
    for (; j + 3 < end; j += 4) {
      int s0 = nbr[j], s1 = nbr[j + 1], s2 = nbr[j + 2], s3 = nbr[j + 3];
      sum += A[(size_t)s0 * 128 + c];
      sum += A[(size_t)s1 * 128 + c];
      sum += A[(size_t)s2 * 128 + c];
      sum += A[(size_t)s3 * 128 + c];
    }
    for (; j < end; ++j) sum += A[(size_t)nbr[j] * 128 + c];
    float y = dinv[i] * sum + bias;
    out[(size_t)i * 128 + c] = fmaxf(y * scale + shift, 0.f);
  }
}

// ---------------- K8: CSR aggregate + BN + ReLU + sorted-batch mean-pool accumulate ----------
__global__ void k_agg_bn_pool(const float* __restrict__ A, const int* __restrict__ nbr,
                              const int* __restrict__ rs, const int* __restrict__ deg,
                              const float* __restrict__ dinv, const int* __restrict__ batch,
                              const float* __restrict__ b, const float* __restrict__ gm,
                              const float* __restrict__ bt, const float* __restrict__ m,
                              const float* __restrict__ v,
                              float* __restrict__ gsum, float* __restrict__ gcnt) {
  int tid = threadIdx.x;
  int c = tid & 127;
  int half = tid >> 7;
  int gid = blockIdx.x * 2 + half;
  if (gid * 32 >= N_NODES) return;
  float scale = gm[c] * rsqrtf(v[c] + EPSBN);
  float shift = bt[c] - m[c] * scale;
  float bias = b[c];
  int base = gid * 32;
  float acc = 0.f, cnt = 0.f;
  int curg = -1;
  for (int nn = 0; nn < 32; ++nn) {
    int i = base + nn;
    int bg = batch[i];
    if (bg != curg) {
      if (curg >= 0) {
        atomicAdd(&gsum[(size_t)curg * 128 + c], acc);
        if (c == 0) atomicAdd(&gcnt[curg], cnt);
      }
      acc = 0.f; cnt = 0.f; curg = bg;
    }
    float sum = A[(size_t)i * 128 + c];
    int j = rs[i];
    int end = j + deg[i] - 1;
    for (; j + 3 < end; j += 4) {
      int s0 = nbr[j], s1 = nbr[j + 1], s2 = nbr[j + 2], s3 = nbr[j + 3];
      sum += A[(size_t)s0 * 128 + c];
      sum += A[(size_t)s1 * 128 + c];
      sum += A[(size_t)s2 * 128 + c];
      sum += A[(size_t)s3 * 128 + c];
    }
    for (; j < end; ++j) sum += A[(size_t)nbr[j] * 128 + c];
    float y = dinv[i] * sum + bias;
    acc += fmaxf(y * scale + shift, 0.f);
    cnt += 1.f;
  }
  atomicAdd(&gsum[(size_t)curg * 128 + c], acc);
  if (c == 0) atomicAdd(&gcnt[curg], cnt);
}

// ---------------- K9: per-graph sum of relu(edge_attr @ We1 + be1), no atomics ----------------
__global__ void k_edge_hidden(const float* __restrict__ edge_attr, const int* __restrict__ ebkt,
                              const int* __restrict__ ebs, const int* __restrict__ ecnt,
                              const float* __restrict__ We1, const float* __restrict__ be1,
                              float* __restrict__ esum) {
  __shared__ float red[128];
  int tid = threadIdx.x;
  int c = tid & 127, half = tid >> 7;
  int g = blockIdx.x;
  float w[16];
  #pragma unroll
  for (int k = 0; k < 16; ++k) w[k] = We1[k * 128 + c];
  float bias = be1[c];
  float acc = 0.f;
  int start = ebs[g], cnt = ecnt[g];
  for (int j = start + half; j < start + cnt; j += 2) {
    int e = ebkt[j];
    const float4* ea = (const float4*)(edge_attr + (size_t)e * 16);
    float4 e0 = ea[0], e1 = ea[1], e2 = ea[2], e3 = ea[3];
    float h = bias;
    h += e0.x * w[0] + e0.y * w[1] + e0.z * w[2] + e0.w * w[3];
    h += e1.x * w[4] + e1.y * w[5] + e1.z * w[6] + e1.w * w[7];
    h += e2.x * w[8] + e2.y * w[9] + e2.z * w[10] + e2.w * w[11];
    h += e3.x * w[12] + e3.y * w[13] + e3.z * w[14] + e3.w * w[15];
    acc += fmaxf(h, 0.f);
  }
  if (half == 1) red[c] = acc;
  __syncthreads();
  if (half == 0) esum[(size_t)g * 128 + c] = acc + red[c];
}

// ---------------- K10: graph mean + (edge mean hidden) @ We2 + be2 -> out ----------------
__global__ void k_final(const float* __restrict__ esum, const int* __restrict__ ecnt,
                        const float* __restrict__ gsum, const float* __restrict__ gcnt,
                        const float* __restrict__ We2, const float* __restrict__ be2,
                        float* __restrict__ out) {
  __shared__ float mh[128];
  int g = blockIdx.x, c = threadIdx.x;
  int ec = ecnt[g];
  mh[c] = (ec > 0) ? esum[(size_t)g * 128 + c] / (float)ec : 0.f;
  __syncthreads();
  float acc = 0.f;
  #pragma unroll 8
  for (int k = 0; k < 128; ++k) acc += mh[k] * We2[k * 128 + c];
  float er = (ec > 0) ? (acc + be2[c]) : 0.f;
  float gr = gsum[(size_t)g * 128 + c] / fmaxf(gcnt[g], 1.f);
  out[(size_t)g * 128 + c] = gr + er;
}

extern "C" void kernel_launch(void* const* d_in, const int* in_sizes, int n_in,
                              void* d_out, int out_size, void* d_ws, size_t ws_size,
                              hipStream_t stream) {
  const float* x        = (const float*)d_in[0];
  const int*   ei       = (const int*)d_in[1];     // [2, E]
  const int*   batch    = (const int*)d_in[2];     // [N], sorted
  const float* edge_attr= (const float*)d_in[3];   // [E, 16]
  // d_in[4] = num_graphs (512), compile-time constant here
  const float* W1 = (const float*)d_in[5];
  const float* b1 = (const float*)d_in[6];
  const float* g1 = (const float*)d_in[7];
  const float* bt1= (const float*)d_in[8];
  const float* m1 = (const float*)d_in[9];
  const float* v1 = (const float*)d_in[10];
  const float* W2 = (const float*)d_in[11];
  const float* b2 = (const float*)d_in[12];
  const float* g2 = (const float*)d_in[13];
  const float* bt2= (const float*)d_in[14];
  const float* m2 = (const float*)d_in[15];
  const float* v2 = (const float*)d_in[16];
  const float* We1= (const float*)d_in[17];
  const float* be1= (const float*)d_in[18];
  const float* We2= (const float*)d_in[19];
  const float* be2= (const float*)d_in[20];
  float* out = (float*)d_out;

  char* ws = (char*)d_ws;
  size_t off = 0;
  auto take = [&](size_t bytes) -> char* {
    char* p = ws + off;
    off += (bytes + 255) & ~(size_t)255;
    return p;
  };
  float* A     = (float*)take((size_t)N_NODES * 128 * 4);
  float* B     = (float*)take((size_t)N_NODES * 128 * 4);
  float* dinv  = (float*)take((size_t)N_NODES * 4);
  int*   deg   = (int*)  take((size_t)N_NODES * 4);
  int*   rs    = (int*)  take((size_t)N_NODES * 4);
  int*   cursor= (int*)  take((size_t)N_NODES * 4);
  int*   nbr   = (int*)  take((size_t)(N_EDGES + N_NODES) * 4); // CSR slots incl. self-loop gaps
  int*   ebkt  = (int*)  take((size_t)N_EDGES * 4);
  int*   ecnt  = (int*)  take((size_t)G * 4);
  int*   ebs   = (int*)  take((size_t)G * 4);
  int*   ecur  = (int*)  take((size_t)G * 4);
  float* gcnt  = (float*)take((size_t)G * 4);
  float* esum  = (float*)take((size_t)G * 128 * 4);
  float* gsum  = (float*)take((size_t)G * 128 * 4);

  k_init<<<(N_NODES + 255) / 256, 256, 0, stream>>>(deg, ecnt, gcnt, gsum);
  k_count<<<(N_EDGES + 4095) / 4096, 256, 0, stream>>>(ei, batch, deg, ecnt);
  k_scan<<<1, 1024, 0, stream>>>(deg, rs, cursor, ecnt, ebs, ecur);
  k_dinv<<<(N_NODES + 255) / 256, 256, 0, stream>>>(deg, dinv);
  k_scatter<<<(N_EDGES + 255) / 256, 256, 0, stream>>>(ei, batch, cursor, ecur, nbr, ebkt);
  // layer 1
  k_gemm_scale<<<(N_NODES + 127) / 128, 256, 0, stream>>>(x, W1, dinv, A);
  k_agg_bn<<<(N_NODES / 32 + 1) / 2 + 1, 256, 0, stream>>>(A, nbr, rs, deg, dinv, b1, g1, bt1, m1, v1, B);
  // layer 2 (+ pooling fused)
  k_gemm_scale<<<(N_NODES + 127) / 128, 256, 0, stream>>>(B, W2, dinv, A);
  k_agg_bn_pool<<<(N_NODES / 32 + 1) / 2 + 1, 256, 0, stream>>>(A, nbr, rs, deg, dinv, batch, b2, g2, bt2, m2, v2, gsum, gcnt);
  // edge path
  k_edge_hidden<<<G, 256, 0, stream>>>(edge_attr, ebkt, ebs, ecnt, We1, be1, esum);
  k_final<<<G, 128, 0, stream>>>(esum, ecnt, gsum, gcnt, We2, be2, out);
}

// Round 2
// 1907.118 us; speedup vs baseline: 1.4321x; 1.4321x over previous
//
#include <hip/hip_runtime.h>

#define N_NODES 100000
#define N_EDGES 1600000
#define D 128
#define DE 16
#define G 512
#define EPSBN 1e-5f
#define ESLICE 16   // blocks per graph in k_edge_hidden

// ---------------- K0: init deg=1 (self loop), zero counters/accumulators ----------------
__global__ void k_init(int* __restrict__ deg, int* __restrict__ ecnt,
                       float* __restrict__ gcnt, float* __restrict__ gsum,
                       float* __restrict__ esum) {
  int i = blockIdx.x * 256 + threadIdx.x;
  if (i < N_NODES) deg[i] = 1;
  if (i < G) { ecnt[i] = 0; gcnt[i] = 0.f; }
  if (i < G * D) { gsum[i] = 0.f; esum[i] = 0.f; }
}

// ---------------- K1: count in-degree per node + edges per graph (LDS bins) ----------------
__global__ void k_count(const int* __restrict__ ei, const int* __restrict__ batch,
                        int* __restrict__ deg, int* __restrict__ ecnt) {
  __shared__ int bins[G];
  int tid = threadIdx.x;
  for (int i = tid; i < G; i += 256) bins[i] = 0;
  __syncthreads();
  int base = blockIdx.x * 4096;
  for (int t = tid; t < 4096; t += 256) {
    int e = base + t;
    if (e < N_EDGES) {
      int s = ei[e];
      int d = ei[N_EDGES + e];
      atomicAdd(&deg[d], 1);
      atomicAdd(&bins[batch[s]], 1);
    }
  }
  __syncthreads();
  for (int i = tid; i < G; i += 256) if (bins[i]) atomicAdd(&ecnt[i], bins[i]);
}

// ---------------- K2: single-block exclusive scans (node CSR starts + graph bucket starts) ----
__global__ void k_scan(const int* __restrict__ deg, int* __restrict__ rs, int* __restrict__ cursor,
                       const int* __restrict__ ecnt, int* __restrict__ ebs, int* __restrict__ ecur) {
  __shared__ int sb[1024];
  int tid = threadIdx.x;
  const int chunk = (N_NODES + 1023) / 1024;  // 98
  int start = tid * chunk;
  int end = start + chunk; if (end > N_NODES) end = N_NODES;
  int s = 0;
  for (int i = start; i < end; ++i) s += deg[i];
  sb[tid] = s;
  __syncthreads();
  for (int off = 1; off < 1024; off <<= 1) {
    int t = (tid >= off) ? sb[tid - off] : 0;
    __syncthreads();
    sb[tid] += t;
    __syncthreads();
  }
  int run = sb[tid] - s;  // exclusive prefix of this chunk
  for (int i = start; i < end; ++i) { rs[i] = run; cursor[i] = run; run += deg[i]; }
  __syncthreads();
  int v2 = (tid < G) ? ecnt[tid] : 0;
  sb[tid] = v2;
  __syncthreads();
  for (int off = 1; off < 1024; off <<= 1) {
    int t = (tid >= off) ? sb[tid - off] : 0;
    __syncthreads();
    sb[tid] += t;
    __syncthreads();
  }
  if (tid < G) { ebs[tid] = sb[tid] - v2; ecur[tid] = sb[tid] - v2; }
}

// ---------------- K3: dinv = rsqrt(deg) ----------------
__global__ void k_dinv(const int* __restrict__ deg, float* __restrict__ dinv) {
  int i = blockIdx.x * 256 + threadIdx.x;
  if (i < N_NODES) dinv[i] = rsqrtf((float)deg[i]);
}

// ---------------- K4: scatter edges into node-CSR and graph buckets ----------------
__global__ void k_scatter(const int* __restrict__ ei, const int* __restrict__ batch,
                          int* __restrict__ cursor, int* __restrict__ ecur,
                          int* __restrict__ nbr, int* __restrict__ ebkt) {
  int e = blockIdx.x * 256 + threadIdx.x;
  if (e >= N_EDGES) return;
  int s = ei[e], d = ei[N_EDGES + e];
  int pos = atomicAdd(&cursor[d], 1);
  nbr[pos] = s;
  int ep = atomicAdd(&ecur[batch[s]], 1);
  ebkt[ep] = e;
}

// ---------------- K5/K7: out = (X @ W) * dinv[row]   (N x 128 @ 128 x 128, fp32) -------------
__global__ __launch_bounds__(256) void k_gemm_scale(const float* __restrict__ X,
                                                    const float* __restrict__ W,
                                                    const float* __restrict__ dinv,
                                                    float* __restrict__ out) {
  __shared__ float sX[128][32];
  __shared__ float sW[32][128];
  int tid = threadIdx.x;
  int tx = tid & 15, ty = tid >> 4;
  int rowBase = blockIdx.x * 128;
  float acc[8][8] = {};
  for (int kc = 0; kc < 128; kc += 32) {
    #pragma unroll
    for (int i = 0; i < 4; ++i) {
      int idx = tid + i * 256;          // 0..1023 -> 128 rows x 8 float4
      int r = idx >> 3, kq = idx & 7;
      int row = rowBase + r;
      float4 v = make_float4(0.f, 0.f, 0.f, 0.f);
      if (row < N_NODES) v = *(const float4*)(X + (size_t)row * 128 + kc + kq * 4);
      *(float4*)(&sX[r][kq * 4]) = v;
    }
    #pragma unroll
    for (int i = 0; i < 4; ++i) {
      int idx = tid + i * 256;          // 32 rows x 32 float4
      int k = idx >> 5, cq = idx & 31;
      *(float4*)(&sW[k][cq * 4]) = *(const float4*)(W + (size_t)(kc + k) * 128 + cq * 4);
    }
    __syncthreads();
    #pragma unroll 4
    for (int k = 0; k < 32; ++k) {
      float a[8], b[8];
      #pragma unroll
      for (int j = 0; j < 8; ++j) a[j] = sX[ty * 8 + j][k];
      *(float4*)(&b[0]) = *(float4*)(&sW[k][tx * 8]);
      *(float4*)(&b[4]) = *(float4*)(&sW[k][tx * 8 + 4]);
      #pragma unroll
      for (int j = 0; j < 8; ++j)
        #pragma unroll
        for (int c = 0; c < 8; ++c) acc[j][c] += a[j] * b[c];
    }
    __syncthreads();
  }
  #pragma unroll
  for (int j = 0; j < 8; ++j) {
    int row = rowBase + ty * 8 + j;
    if (row < N_NODES) {
      float dv = dinv[row];
      float4 o0, o1;
      o0.x = acc[j][0] * dv; o0.y = acc[j][1] * dv; o0.z = acc[j][2] * dv; o0.w = acc[j][3] * dv;
      o1.x = acc[j][4] * dv; o1.y = acc[j][5] * dv; o1.z = acc[j][6] * dv; o1.w = acc[j][7] * dv;
      *(float4*)(out + (size_t)row * 128 + tx * 8) = o0;
      *(float4*)(out + (size_t)row * 128 + tx * 8 + 4) = o1;
    }
  }
}

// ---------------- K6: CSR aggregate + bias + BN + ReLU -> out ----------------
__global__ void k_agg_bn(const float* __restrict__ A, const int* __restrict__ nbr,
                         const int* __restrict__ rs, const int* __restrict__ deg,
                         const float* __restrict__ dinv,
                         const float* __restrict__ b, const float* __restrict__ gm,
                         const float* __restrict__ bt, const float* __restrict__ m,
                         const float* __restrict__ v, float* __restrict__ out) {
  int tid = threadIdx.x;
  int c = tid & 127;
  int half = tid >> 7;
  int gid = blockIdx.x * 2 + half;  // 32 nodes per group
  if (gid * 32 >= N_NODES) return;
  float scale = gm[c] * rsqrtf(v[c] + EPSBN);
  float shift = bt[c] - m[c] * scale;
  float bias = b[c];
  int base = gid * 32;
  for (int nn = 0; nn < 32; ++nn) {
    int i = base + nn;
    float sum = A[(size_t)i * 128 + c];   // self loop (already dinv-scaled)
    int j = rs[i];
    int end = j + deg[i] - 1;             // indeg real edges
    for (; j + 3 < end; j += 4) {
      int s0 = nbr[j], s1 = nbr[j + 1], s2 = nbr[j + 2], s3 = nbr[j + 3];
      sum += A[(size_t)s0 * 128 + c];
      sum += A[(size_t)s1 * 128 + c];
      sum += A[(size_t)s2 * 128 + c];
      sum += A[(size_t)s3 * 128 + c];
    }
    for (; j < end; ++j) sum += A[(size_t)nbr[j] * 128 + c];
    float y = dinv[i] * sum + bias;
    out[(size_t)i * 128 + c] = fmaxf(y * scale + shift, 0.f);
  }
}

// ---------------- K8: CSR aggregate + BN + ReLU + sorted-batch mean-pool accumulate ----------
__global__ void k_agg_bn_pool(const float* __restrict__ A, const int* __restrict__ nbr,
                              const int* __restrict__ rs, const int* __restrict__ deg,
                              const float* __restrict__ dinv, const int* __restrict__ batch,
                              const float* __restrict__ b, const float* __restrict__ gm,
                              const float* __restrict__ bt, const float* __restrict__ m,
                              const float* __restrict__ v,
                              float* __restrict__ gsum, float* __restrict__ gcnt) {
  int tid = threadIdx.x;
  int c = tid & 127;
  int half = tid >> 7;
  int gid = blockIdx.x * 2 + half;
  if (gid * 32 >= N_NODES) return;
  float scale = gm[c] * rsqrtf(v[c] + EPSBN);
  float shift = bt[c] - m[c] * scale;
  float bias = b[c];
  int base = gid * 32;
  float acc = 0.f, cnt = 0.f;
  int curg = -1;
  for (int nn = 0; nn < 32; ++nn) {
    int i = base + nn;
    int bg = batch[i];
    if (bg != curg) {
      if (curg >= 0) {
        atomicAdd(&gsum[(size_t)curg * 128 + c], acc);
        if (c == 0) atomicAdd(&gcnt[curg], cnt);
      }
      acc = 0.f; cnt = 0.f; curg = bg;
    }
    float sum = A[(size_t)i * 128 + c];
    int j = rs[i];
    int end = j + deg[i] - 1;
    for (; j + 3 < end; j += 4) {
      int s0 = nbr[j], s1 = nbr[j + 1], s2 = nbr[j + 2], s3 = nbr[j + 3];
      sum += A[(size_t)s0 * 128 + c];
      sum += A[(size_t)s1 * 128 + c];
      sum += A[(size_t)s2 * 128 + c];
      sum += A[(size_t)s3 * 128 + c];
    }
    for (; j < end; ++j) sum += A[(size_t)nbr[j] * 128 + c];
    float y = dinv[i] * sum + bias;
    acc += fmaxf(y * scale + shift, 0.f);
    cnt += 1.f;
  }
  atomicAdd(&gsum[(size_t)curg * 128 + c], acc);
  if (c == 0) atomicAdd(&gcnt[curg], cnt);
}

// ---------------- K9: per-graph sum of relu(edge_attr @ We1 + be1) ----------------
// Grid = G*ESLICE blocks; each block handles a contiguous chunk of graph g's edge
// bucket with 2 half-streams; 4-edge unroll for memory-level parallelism.
__global__ __launch_bounds__(256) void k_edge_hidden(
    const float* __restrict__ edge_attr, const int* __restrict__ ebkt,
    const int* __restrict__ ebs, const int* __restrict__ ecnt,
    const float* __restrict__ We1, const float* __restrict__ be1,
    float* __restrict__ esum) {
  __shared__ float red[128];
  int tid = threadIdx.x;
  int c = tid & 127, half = tid >> 7;
  int g = blockIdx.x / ESLICE;
  int slice = blockIdx.x % ESLICE;
  float w[16];
  #pragma unroll
  for (int k = 0; k < 16; ++k) w[k] = We1[k * 128 + c];
  float bias = be1[c];
  int start = ebs[g], cnt = ecnt[g];
  const int nstream = ESLICE * 2;
  int sid = slice * 2 + half;
  int chunk = (cnt + nstream - 1) / nstream;
  int j0 = start + sid * chunk;
  int j1 = j0 + chunk;
  int lim = start + cnt;
  if (j1 > lim) j1 = lim;
  float acc = 0.f;
  int j = j0;
  for (; j + 4 <= j1; j += 4) {
    int e0 = ebkt[j], e1 = ebkt[j + 1], e2 = ebkt[j + 2], e3 = ebkt[j + 3];
    const float4* p0 = (const float4*)(edge_attr + (size_t)e0 * 16);
    const float4* p1 = (const float4*)(edge_attr + (size_t)e1 * 16);
    const float4* p2 = (const float4*)(edge_attr + (size_t)e2 * 16);
    const float4* p3 = (const float4*)(edge_attr + (size_t)e3 * 16);
    float4 a0 = p0[0], a1 = p0[1], a2 = p0[2], a3 = p0[3];
    float4 b0 = p1[0], b1 = p1[1], b2 = p1[2], b3 = p1[3];
    float4 c0 = p2[0], c1 = p2[1], c2 = p2[2], c3 = p2[3];
    float4 d0 = p3[0], d1 = p3[1], d2 = p3[2], d3 = p3[3];
    float h0 = bias, h1 = bias, h2 = bias, h3 = bias;
    h0 += a0.x*w[0]+a0.y*w[1]+a0.z*w[2]+a0.w*w[3] + a1.x*w[4]+a1.y*w[5]+a1.z*w[6]+a1.w*w[7]
        + a2.x*w[8]+a2.y*w[9]+a2.z*w[10]+a2.w*w[11] + a3.x*w[12]+a3.y*w[13]+a3.z*w[14]+a3.w*w[15];
    h1 += b0.x*w[0]+b0.y*w[1]+b0.z*w[2]+b0.w*w[3] + b1.x*w[4]+b1.y*w[5]+b1.z*w[6]+b1.w*w[7]
        + b2.x*w[8]+b2.y*w[9]+b2.z*w[10]+b2.w*w[11] + b3.x*w[12]+b3.y*w[13]+b3.z*w[14]+b3.w*w[15];
    h2 += c0.x*w[0]+c0.y*w[1]+c0.z*w[2]+c0.w*w[3] + c1.x*w[4]+c1.y*w[5]+c1.z*w[6]+c1.w*w[7]
        + c2.x*w[8]+c2.y*w[9]+c2.z*w[10]+c2.w*w[11] + c3.x*w[12]+c3.y*w[13]+c3.z*w[14]+c3.w*w[15];
    h3 += d0.x*w[0]+d0.y*w[1]+d0.z*w[2]+d0.w*w[3] + d1.x*w[4]+d1.y*w[5]+d1.z*w[6]+d1.w*w[7]
        + d2.x*w[8]+d2.y*w[9]+d2.z*w[10]+d2.w*w[11] + d3.x*w[12]+d3.y*w[13]+d3.z*w[14]+d3.w*w[15];
    acc += fmaxf(h0, 0.f) + fmaxf(h1, 0.f) + fmaxf(h2, 0.f) + fmaxf(h3, 0.f);
  }
  for (; j < j1; ++j) {
    int e = ebkt[j];
    const float4* ea = (const float4*)(edge_attr + (size_t)e * 16);
    float4 e0 = ea[0], e1 = ea[1], e2 = ea[2], e3 = ea[3];
    float h = bias;
    h += e0.x*w[0]+e0.y*w[1]+e0.z*w[2]+e0.w*w[3] + e1.x*w[4]+e1.y*w[5]+e1.z*w[6]+e1.w*w[7]
       + e2.x*w[8]+e2.y*w[9]+e2.z*w[10]+e2.w*w[11] + e3.x*w[12]+e3.y*w[13]+e3.z*w[14]+e3.w*w[15];
    acc += fmaxf(h, 0.f);
  }
  if (half == 1) red[c] = acc;
  __syncthreads();
  if (half == 0) {
    float total = acc + red[c];
    atomicAdd(&esum[(size_t)g * 128 + c], total);
  }
}

// ---------------- K10: graph mean + (edge mean hidden) @ We2 + be2 -> out ----------------
__global__ void k_final(const float* __restrict__ esum, const int* __restrict__ ecnt,
                        const float* __restrict__ gsum, const float* __restrict__ gcnt,
                        const float* __restrict__ We2, const float* __restrict__ be2,
                        float* __restrict__ out) {
  __shared__ float mh[128];
  int g = blockIdx.x, c = threadIdx.x;
  int ec = ecnt[g];
  mh[c] = (ec > 0) ? esum[(size_t)g * 128 + c] / (float)ec : 0.f;
  __syncthreads();
  float acc = 0.f;
  #pragma unroll 8
  for (int k = 0; k < 128; ++k) acc += mh[k] * We2[k * 128 + c];
  float er = (ec > 0) ? (acc + be2[c]) : 0.f;
  float gr = gsum[(size_t)g * 128 + c] / fmaxf(gcnt[g], 1.f);
  out[(size_t)g * 128 + c] = gr + er;
}

extern "C" void kernel_launch(void* const* d_in, const int* in_sizes, int n_in,
                              void* d_out, int out_size, void* d_ws, size_t ws_size,
                              hipStream_t stream) {
  const float* x        = (const float*)d_in[0];
  const int*   ei       = (const int*)d_in[1];     // [2, E]
  const int*   batch    = (const int*)d_in[2];     // [N], sorted
  const float* edge_attr= (const float*)d_in[3];   // [E, 16]
  // d_in[4] = num_graphs (512), compile-time constant here
  const float* W1 = (const float*)d_in[5];
  const float* b1 = (const float*)d_in[6];
  const float* g1 = (const float*)d_in[7];
  const float* bt1= (const float*)d_in[8];
  const float* m1 = (const float*)d_in[9];
  const float* v1 = (const float*)d_in[10];
  const float* W2 = (const float*)d_in[11];
  const float* b2 = (const float*)d_in[12];
  const float* g2 = (const float*)d_in[13];
  const float* bt2= (const float*)d_in[14];
  const float* m2 = (const float*)d_in[15];
  const float* v2 = (const float*)d_in[16];
  const float* We1= (const float*)d_in[17];
  const float* be1= (const float*)d_in[18];
  const float* We2= (const float*)d_in[19];
  const float* be2= (const float*)d_in[20];
  float* out = (float*)d_out;

  char* ws = (char*)d_ws;
  size_t off = 0;
  auto take = [&](size_t bytes) -> char* {
    char* p = ws + off;
    off += (bytes + 255) & ~(size_t)255;
    return p;
  };
  float* A     = (float*)take((size_t)N_NODES * 128 * 4);
  float* B     = (float*)take((size_t)N_NODES * 128 * 4);
  float* dinv  = (float*)take((size_t)N_NODES * 4);
  int*   deg   = (int*)  take((size_t)N_NODES * 4);
  int*   rs    = (int*)  take((size_t)N_NODES * 4);
  int*   cursor= (int*)  take((size_t)N_NODES * 4);
  int*   nbr   = (int*)  take((size_t)(N_EDGES + N_NODES) * 4);
  int*   ebkt  = (int*)  take((size_t)N_EDGES * 4);
  int*   ecnt  = (int*)  take((size_t)G * 4);
  int*   ebs   = (int*)  take((size_t)G * 4);
  int*   ecur  = (int*)  take((size_t)G * 4);
  float* gcnt  = (float*)take((size_t)G * 4);
  float* esum  = (float*)take((size_t)G * 128 * 4);
  float* gsum  = (float*)take((size_t)G * 128 * 4);

  k_init<<<(N_NODES + 255) / 256, 256, 0, stream>>>(deg, ecnt, gcnt, gsum, esum);
  k_count<<<(N_EDGES + 4095) / 4096, 256, 0, stream>>>(ei, batch, deg, ecnt);
  k_scan<<<1, 1024, 0, stream>>>(deg, rs, cursor, ecnt, ebs, ecur);
  k_dinv<<<(N_NODES + 255) / 256, 256, 0, stream>>>(deg, dinv);
  k_scatter<<<(N_EDGES + 255) / 256, 256, 0, stream>>>(ei, batch, cursor, ecur, nbr, ebkt);
  // layer 1
  k_gemm_scale<<<(N_NODES + 127) / 128, 256, 0, stream>>>(x, W1, dinv, A);
  k_agg_bn<<<(N_NODES / 32 + 1) / 2 + 1, 256, 0, stream>>>(A, nbr, rs, deg, dinv, b1, g1, bt1, m1, v1, B);
  // layer 2 (+ pooling fused)
  k_gemm_scale<<<(N_NODES + 127) / 128, 256, 0, stream>>>(B, W2, dinv, A);
  k_agg_bn_pool<<<(N_NODES / 32 + 1) / 2 + 1, 256, 0, stream>>>(A, nbr, rs, deg, dinv, batch, b2, g2, bt2, m2, v2, gsum, gcnt);
  // edge path
  k_edge_hidden<<<G * ESLICE, 256, 0, stream>>>(edge_attr, ebkt, ebs, ecnt, We1, be1, esum);
  k_final<<<G, 128, 0, stream>>>(esum, ecnt, gsum, gcnt, We2, be2, out);
}

// Round 3
// 1502.059 us; speedup vs baseline: 1.8183x; 1.2697x over previous
//
#include <hip/hip_runtime.h>

#define N_NODES 100000
#define N_EDGES 1600000
#define D 128
#define DE 16
#define G 512
#define EPSBN 1e-5f
#define ESLICE 16   // blocks per graph in k_edge_hidden
#define EPB 2048    // edges per block in k_scatter
#define EPT (EPB / 256)

// ---------------- K0: init deg=1 (self loop), zero counters/accumulators ----------------
__global__ void k_init(int* __restrict__ deg, int* __restrict__ ecnt,
                       float* __restrict__ gcnt, float* __restrict__ gsum,
                       float* __restrict__ esum) {
  int i = blockIdx.x * 256 + threadIdx.x;
  if (i < N_NODES) deg[i] = 1;
  if (i < G) { ecnt[i] = 0; gcnt[i] = 0.f; }
  if (i < G * D) { gsum[i] = 0.f; esum[i] = 0.f; }
}

// ---------------- K1: count in-degree per node + edges per graph (LDS bins) ----------------
__global__ void k_count(const int* __restrict__ ei, const int* __restrict__ batch,
                        int* __restrict__ deg, int* __restrict__ ecnt) {
  __shared__ int bins[G];
  int tid = threadIdx.x;
  for (int i = tid; i < G; i += 256) bins[i] = 0;
  __syncthreads();
  int base = blockIdx.x * 4096;
  for (int t = tid; t < 4096; t += 256) {
    int e = base + t;
    if (e < N_EDGES) {
      int s = ei[e];
      int d = ei[N_EDGES + e];
      atomicAdd(&deg[d], 1);
      atomicAdd(&bins[batch[s]], 1);
    }
  }
  __syncthreads();
  for (int i = tid; i < G; i += 256) if (bins[i]) atomicAdd(&ecnt[i], bins[i]);
}

// ---------------- K2: single-block exclusive scans (node CSR starts + graph bucket starts) ----
// ecur_pad: one cursor per 64B cache line (stride 16 ints) to kill L2 line contention.
__global__ void k_scan(const int* __restrict__ deg, int* __restrict__ rs, int* __restrict__ cursor,
                       const int* __restrict__ ecnt, int* __restrict__ ebs, int* __restrict__ ecur_pad) {
  __shared__ int sb[1024];
  int tid = threadIdx.x;
  const int chunk = (N_NODES + 1023) / 1024;  // 98
  int start = tid * chunk;
  int end = start + chunk; if (end > N_NODES) end = N_NODES;
  int s = 0;
  for (int i = start; i < end; ++i) s += deg[i];
  sb[tid] = s;
  __syncthreads();
  for (int off = 1; off < 1024; off <<= 1) {
    int t = (tid >= off) ? sb[tid - off] : 0;
    __syncthreads();
    sb[tid] += t;
    __syncthreads();
  }
  int run = sb[tid] - s;  // exclusive prefix of this chunk
  for (int i = start; i < end; ++i) { rs[i] = run; cursor[i] = run; run += deg[i]; }
  __syncthreads();
  int v2 = (tid < G) ? ecnt[tid] : 0;
  sb[tid] = v2;
  __syncthreads();
  for (int off = 1; off < 1024; off <<= 1) {
    int t = (tid >= off) ? sb[tid - off] : 0;
    __syncthreads();
    sb[tid] += t;
    __syncthreads();
  }
  if (tid < G) { ebs[tid] = sb[tid] - v2; ecur_pad[tid * 16] = sb[tid] - v2; }
}

// ---------------- K3: dinv = rsqrt(deg) ----------------
__global__ void k_dinv(const int* __restrict__ deg, float* __restrict__ dinv) {
  int i = blockIdx.x * 256 + threadIdx.x;
  if (i < N_NODES) dinv[i] = rsqrtf((float)deg[i]);
}

// ---------------- K4: scatter edges into node-CSR (atomic cursors) and graph buckets
// (block-local counting sort: LDS ranks + one padded global reservation per bin) ------------
__global__ __launch_bounds__(256) void k_scatter(const int* __restrict__ ei,
                                                 const int* __restrict__ batch,
                                                 int* __restrict__ cursor,
                                                 int* __restrict__ ecur_pad,
                                                 int* __restrict__ nbr,
                                                 int* __restrict__ ebkt) {
  __shared__ int bins[G];
  __shared__ int base[G];
  int tid = threadIdx.x;
  for (int i = tid; i < G; i += 256) bins[i] = 0;
  __syncthreads();
  int e0 = blockIdx.x * EPB;
  int ge[EPT], gr[EPT];
  #pragma unroll
  for (int k = 0; k < EPT; ++k) {
    int e = e0 + k * 256 + tid;
    ge[k] = -1;
    if (e < N_EDGES) {
      int s = ei[e], d = ei[N_EDGES + e];
      int pos = atomicAdd(&cursor[d], 1);   // ~16 ops/address, ~256/line: cheap
      nbr[pos] = s;
      int g = batch[s];
      ge[k] = g;
      gr[k] = atomicAdd(&bins[g], 1);       // LDS atomic, intra-block rank
    }
  }
  __syncthreads();
  for (int i = tid; i < G; i += 256) {
    int cnt = bins[i];
    base[i] = cnt ? atomicAdd(&ecur_pad[i * 16], cnt) : 0;  // 1 global atomic per (block,bin)
  }
  __syncthreads();
  #pragma unroll
  for (int k = 0; k < EPT; ++k) {
    if (ge[k] >= 0) {
      int e = e0 + k * 256 + tid;
      ebkt[base[ge[k]] + gr[k]] = e;
    }
  }
}

// ---------------- K5/K7: out = (X @ W) * dinv[row]   (N x 128 @ 128 x 128, fp32) -------------
__global__ __launch_bounds__(256) void k_gemm_scale(const float* __restrict__ X,
                                                    const float* __restrict__ W,
                                                    const float* __restrict__ dinv,
                                                    float* __restrict__ out) {
  __shared__ float sX[128][32];
  __shared__ float sW[32][128];
  int tid = threadIdx.x;
  int tx = tid & 15, ty = tid >> 4;
  int rowBase = blockIdx.x * 128;
  float acc[8][8] = {};
  for (int kc = 0; kc < 128; kc += 32) {
    #pragma unroll
    for (int i = 0; i < 4; ++i) {
      int idx = tid + i * 256;          // 0..1023 -> 128 rows x 8 float4
      int r = idx >> 3, kq = idx & 7;
      int row = rowBase + r;
      float4 v = make_float4(0.f, 0.f, 0.f, 0.f);
      if (row < N_NODES) v = *(const float4*)(X + (size_t)row * 128 + kc + kq * 4);
      *(float4*)(&sX[r][kq * 4]) = v;
    }
    #pragma unroll
    for (int i = 0; i < 4; ++i) {
      int idx = tid + i * 256;          // 32 rows x 32 float4
      int k = idx >> 5, cq = idx & 31;
      *(float4*)(&sW[k][cq * 4]) = *(const float4*)(W + (size_t)(kc + k) * 128 + cq * 4);
    }
    __syncthreads();
    #pragma unroll 4
    for (int k = 0; k < 32; ++k) {
      float a[8], b[8];
      #pragma unroll
      for (int j = 0; j < 8; ++j) a[j] = sX[ty * 8 + j][k];
      *(float4*)(&b[0]) = *(float4*)(&sW[k][tx * 8]);
      *(float4*)(&b[4]) = *(float4*)(&sW[k][tx * 8 + 4]);
      #pragma unroll
      for (int j = 0; j < 8; ++j)
        #pragma unroll
        for (int c = 0; c < 8; ++c) acc[j][c] += a[j] * b[c];
    }
    __syncthreads();
  }
  #pragma unroll
  for (int j = 0; j < 8; ++j) {
    int row = rowBase + ty * 8 + j;
    if (row < N_NODES) {
      float dv = dinv[row];
      float4 o0, o1;
      o0.x = acc[j][0] * dv; o0.y = acc[j][1] * dv; o0.z = acc[j][2] * dv; o0.w = acc[j][3] * dv;
      o1.x = acc[j][4] * dv; o1.y = acc[j][5] * dv; o1.z = acc[j][6] * dv; o1.w = acc[j][7] * dv;
      *(float4*)(out + (size_t)row * 128 + tx * 8) = o0;
      *(float4*)(out + (size_t)row * 128 + tx * 8 + 4) = o1;
    }
  }
}

// ---------------- K6: CSR aggregate + bias + BN + ReLU -> out ----------------
__global__ void k_agg_bn(const float* __restrict__ A, const int* __restrict__ nbr,
                         const int* __restrict__ rs, const int* __restrict__ deg,
                         const float* __restrict__ dinv,
                         const float* __restrict__ b, const float* __restrict__ gm,
                         const float* __restrict__ bt, const float* __restrict__ m,
                         const float* __restrict__ v, float* __restrict__ out) {
  int tid = threadIdx.x;
  int c = tid & 127;
  int half = tid >> 7;
  int gid = blockIdx.x * 2 + half;  // 32 nodes per group
  if (gid * 32 >= N_NODES) return;
  float scale = gm[c] * rsqrtf(v[c] + EPSBN);
  float shift = bt[c] - m[c] * scale;
  float bias = b[c];
  int base = gid * 32;
  for (int nn = 0; nn < 32; ++nn) {
    int i = base + nn;
    float sum = A[(size_t)i * 128 + c];   // self loop (already dinv-scaled)
    int j = rs[i];
    int end = j + deg[i] - 1;             // indeg real edges
    for (; j + 3 < end; j += 4) {
      int s0 = nbr[j], s1 = nbr[j + 1], s2 = nbr[j + 2], s3 = nbr[j + 3];
      sum += A[(size_t)s0 * 128 + c];
      sum += A[(size_t)s1 * 128 + c];
      sum += A[(size_t)s2 * 128 + c];
      sum += A[(size_t)s3 * 128 + c];
    }
    for (; j < end; ++j) sum += A[(size_t)nbr[j] * 128 + c];
    float y = dinv[i] * sum + bias;
    out[(size_t)i * 128 + c] = fmaxf(y * scale + shift, 0.f);
  }
}

// ---------------- K8: CSR aggregate + BN + ReLU + sorted-batch mean-pool accumulate ----------
__global__ void k_agg_bn_pool(const float* __restrict__ A, const int* __restrict__ nbr,
                              const int* __restrict__ rs, const int* __restrict__ deg,
                              const float* __restrict__ dinv, const int* __restrict__ batch,
                              const float* __restrict__ b, const float* __restrict__ gm,
                              const float* __restrict__ bt, const float* __restrict__ m,
                              const float* __restrict__ v,
                              float* __restrict__ gsum, float* __restrict__ gcnt) {
  int tid = threadIdx.x;
  int c = tid & 127;
  int half = tid >> 7;
  int gid = blockIdx.x * 2 + half;
  if (gid * 32 >= N_NODES) return;
  float scale = gm[c] * rsqrtf(v[c] + EPSBN);
  float shift = bt[c] - m[c] * scale;
  float bias = b[c];
  int base = gid * 32;
  float acc = 0.f, cnt = 0.f;
  int curg = -1;
  for (int nn = 0; nn < 32; ++nn) {
    int i = base + nn;
    int bg = batch[i];
    if (bg != curg) {
      if (curg >= 0) {
        atomicAdd(&gsum[(size_t)curg * 128 + c], acc);
        if (c == 0) atomicAdd(&gcnt[curg], cnt);
      }
      acc = 0.f; cnt = 0.f; curg = bg;
    }
    float sum = A[(size_t)i * 128 + c];
    int j = rs[i];
    int end = j + deg[i] - 1;
    for (; j + 3 < end; j += 4) {
      int s0 = nbr[j], s1 = nbr[j + 1], s2 = nbr[j + 2], s3 = nbr[j + 3];
      sum += A[(size_t)s0 * 128 + c];
      sum += A[(size_t)s1 * 128 + c];
      sum += A[(size_t)s2 * 128 + c];
      sum += A[(size_t)s3 * 128 + c];
    }
    for (; j < end; ++j) sum += A[(size_t)nbr[j] * 128 + c];
    float y = dinv[i] * sum + bias;
    acc += fmaxf(y * scale + shift, 0.f);
    cnt += 1.f;
  }
  atomicAdd(&gsum[(size_t)curg * 128 + c], acc);
  if (c == 0) atomicAdd(&gcnt[curg], cnt);
}

// ---------------- K9: per-graph sum of relu(edge_attr @ We1 + be1) ----------------
__global__ __launch_bounds__(256) void k_edge_hidden(
    const float* __restrict__ edge_attr, const int* __restrict__ ebkt,
    const int* __restrict__ ebs, const int* __restrict__ ecnt,
    const float* __restrict__ We1, const float* __restrict__ be1,
    float* __restrict__ esum) {
  __shared__ float red[128];
  int tid = threadIdx.x;
  int c = tid & 127, half = tid >> 7;
  int g = blockIdx.x / ESLICE;
  int slice = blockIdx.x % ESLICE;
  float w[16];
  #pragma unroll
  for (int k = 0; k < 16; ++k) w[k] = We1[k * 128 + c];
  float bias = be1[c];
  int start = ebs[g], cnt = ecnt[g];
  const int nstream = ESLICE * 2;
  int sid = slice * 2 + half;
  int chunk = (cnt + nstream - 1) / nstream;
  int j0 = start + sid * chunk;
  int j1 = j0 + chunk;
  int lim = start + cnt;
  if (j1 > lim) j1 = lim;
  float acc = 0.f;
  int j = j0;
  for (; j + 4 <= j1; j += 4) {
    int e0 = ebkt[j], e1 = ebkt[j + 1], e2 = ebkt[j + 2], e3 = ebkt[j + 3];
    const float4* p0 = (const float4*)(edge_attr + (size_t)e0 * 16);
    const float4* p1 = (const float4*)(edge_attr + (size_t)e1 * 16);
    const float4* p2 = (const float4*)(edge_attr + (size_t)e2 * 16);
    const float4* p3 = (const float4*)(edge_attr + (size_t)e3 * 16);
    float4 a0 = p0[0], a1 = p0[1], a2 = p0[2], a3 = p0[3];
    float4 b0 = p1[0], b1 = p1[1], b2 = p1[2], b3 = p1[3];
    float4 c0 = p2[0], c1 = p2[1], c2 = p2[2], c3 = p2[3];
    float4 d0 = p3[0], d1 = p3[1], d2 = p3[2], d3 = p3[3];
    float h0 = bias, h1 = bias, h2 = bias, h3 = bias;
    h0 += a0.x*w[0]+a0.y*w[1]+a0.z*w[2]+a0.w*w[3] + a1.x*w[4]+a1.y*w[5]+a1.z*w[6]+a1.w*w[7]
        + a2.x*w[8]+a2.y*w[9]+a2.z*w[10]+a2.w*w[11] + a3.x*w[12]+a3.y*w[13]+a3.z*w[14]+a3.w*w[15];
    h1 += b0.x*w[0]+b0.y*w[1]+b0.z*w[2]+b0.w*w[3] + b1.x*w[4]+b1.y*w[5]+b1.z*w[6]+b1.w*w[7]
        + b2.x*w[8]+b2.y*w[9]+b2.z*w[10]+b2.w*w[11] + b3.x*w[12]+b3.y*w[13]+b3.z*w[14]+b3.w*w[15];
    h2 += c0.x*w[0]+c0.y*w[1]+c0.z*w[2]+c0.w*w[3] + c1.x*w[4]+c1.y*w[5]+c1.z*w[6]+c1.w*w[7]
        + c2.x*w[8]+c2.y*w[9]+c2.z*w[10]+c2.w*w[11] + c3.x*w[12]+c3.y*w[13]+c3.z*w[14]+c3.w*w[15];
    h3 += d0.x*w[0]+d0.y*w[1]+d0.z*w[2]+d0.w*w[3] + d1.x*w[4]+d1.y*w[5]+d1.z*w[6]+d1.w*w[7]
        + d2.x*w[8]+d2.y*w[9]+d2.z*w[10]+d2.w*w[11] + d3.x*w[12]+d3.y*w[13]+d3.z*w[14]+d3.w*w[15];
    acc += fmaxf(h0, 0.f) + fmaxf(h1, 0.f) + fmaxf(h2, 0.f) + fmaxf(h3, 0.f);
  }
  for (; j < j1; ++j) {
    int e = ebkt[j];
    const float4* ea = (const float4*)(edge_attr + (size_t)e * 16);
    float4 e0 = ea[0], e1 = ea[1], e2 = ea[2], e3 = ea[3];
    float h = bias;
    h += e0.x*w[0]+e0.y*w[1]+e0.z*w[2]+e0.w*w[3] + e1.x*w[4]+e1.y*w[5]+e1.z*w[6]+e1.w*w[7]
       + e2.x*w[8]+e2.y*w[9]+e2.z*w[10]+e2.w*w[11] + e3.x*w[12]+e3.y*w[13]+e3.z*w[14]+e3.w*w[15];
    acc += fmaxf(h, 0.f);
  }
  if (half == 1) red[c] = acc;
  __syncthreads();
  if (half == 0) {
    float total = acc + red[c];
    atomicAdd(&esum[(size_t)g * 128 + c], total);
  }
}

// ---------------- K10: graph mean + (edge mean hidden) @ We2 + be2 -> out ----------------
__global__ void k_final(const float* __restrict__ esum, const int* __restrict__ ecnt,
                        const float* __restrict__ gsum, const float* __restrict__ gcnt,
                        const float* __restrict__ We2, const float* __restrict__ be2,
                        float* __restrict__ out) {
  __shared__ float mh[128];
  int g = blockIdx.x, c = threadIdx.x;
  int ec = ecnt[g];
  mh[c] = (ec > 0) ? esum[(size_t)g * 128 + c] / (float)ec : 0.f;
  __syncthreads();
  float acc = 0.f;
  #pragma unroll 8
  for (int k = 0; k < 128; ++k) acc += mh[k] * We2[k * 128 + c];
  float er = (ec > 0) ? (acc + be2[c]) : 0.f;
  float gr = gsum[(size_t)g * 128 + c] / fmaxf(gcnt[g], 1.f);
  out[(size_t)g * 128 + c] = gr + er;
}

extern "C" void kernel_launch(void* const* d_in, const int* in_sizes, int n_in,
                              void* d_out, int out_size, void* d_ws, size_t ws_size,
                              hipStream_t stream) {
  const float* x        = (const float*)d_in[0];
  const int*   ei       = (const int*)d_in[1];     // [2, E]
  const int*   batch    = (const int*)d_in[2];     // [N], sorted
  const float* edge_attr= (const float*)d_in[3];   // [E, 16]
  // d_in[4] = num_graphs (512), compile-time constant here
  const float* W1 = (const float*)d_in[5];
  const float* b1 = (const float*)d_in[6];
  const float* g1 = (const float*)d_in[7];
  const float* bt1= (const float*)d_in[8];
  const float* m1 = (const float*)d_in[9];
  const float* v1 = (const float*)d_in[10];
  const float* W2 = (const float*)d_in[11];
  const float* b2 = (const float*)d_in[12];
  const float* g2 = (const float*)d_in[13];
  const float* bt2= (const float*)d_in[14];
  const float* m2 = (const float*)d_in[15];
  const float* v2 = (const float*)d_in[16];
  const float* We1= (const float*)d_in[17];
  const float* be1= (const float*)d_in[18];
  const float* We2= (const float*)d_in[19];
  const float* be2= (const float*)d_in[20];
  float* out = (float*)d_out;

  char* ws = (char*)d_ws;
  size_t off = 0;
  auto take = [&](size_t bytes) -> char* {
    char* p = ws + off;
    off += (bytes + 255) & ~(size_t)255;
    return p;
  };
  float* A       = (float*)take((size_t)N_NODES * 128 * 4);
  float* B       = (float*)take((size_t)N_NODES * 128 * 4);
  float* dinv    = (float*)take((size_t)N_NODES * 4);
  int*   deg     = (int*)  take((size_t)N_NODES * 4);
  int*   rs      = (int*)  take((size_t)N_NODES * 4);
  int*   cursor  = (int*)  take((size_t)N_NODES * 4);
  int*   nbr     = (int*)  take((size_t)(N_EDGES + N_NODES) * 4);
  int*   ebkt    = (int*)  take((size_t)N_EDGES * 4);
  int*   ecnt    = (int*)  take((size_t)G * 4);
  int*   ebs     = (int*)  take((size_t)G * 4);
  int*   ecur_pad= (int*)  take((size_t)G * 16 * 4);  // 64B-stride cursors
  float* gcnt    = (float*)take((size_t)G * 4);
  float* esum    = (float*)take((size_t)G * 128 * 4);
  float* gsum    = (float*)take((size_t)G * 128 * 4);

  k_init<<<(N_NODES + 255) / 256, 256, 0, stream>>>(deg, ecnt, gcnt, gsum, esum);
  k_count<<<(N_EDGES + 4095) / 4096, 256, 0, stream>>>(ei, batch, deg, ecnt);
  k_scan<<<1, 1024, 0, stream>>>(deg, rs, cursor, ecnt, ebs, ecur_pad);
  k_dinv<<<(N_NODES + 255) / 256, 256, 0, stream>>>(deg, dinv);
  k_scatter<<<(N_EDGES + EPB - 1) / EPB, 256, 0, stream>>>(ei, batch, cursor, ecur_pad, nbr, ebkt);
  // layer 1
  k_gemm_scale<<<(N_NODES + 127) / 128, 256, 0, stream>>>(x, W1, dinv, A);
  k_agg_bn<<<(N_NODES / 32 + 1) / 2 + 1, 256, 0, stream>>>(A, nbr, rs, deg, dinv, b1, g1, bt1, m1, v1, B);
  // layer 2 (+ pooling fused)
  k_gemm_scale<<<(N_NODES + 127) / 128, 256, 0, stream>>>(B, W2, dinv, A);
  k_agg_bn_pool<<<(N_NODES / 32 + 1) / 2 + 1, 256, 0, stream>>>(A, nbr, rs, deg, dinv, batch, b2, g2, bt2, m2, v2, gsum, gcnt);
  // edge path
  k_edge_hidden<<<G * ESLICE, 256, 0, stream>>>(edge_attr, ebkt, ebs, ecnt, We1, be1, esum);
  k_final<<<G, 128, 0, stream>>>(esum, ecnt, gsum, gcnt, We2, be2, out);
}

// Round 4
// 1221.085 us; speedup vs baseline: 2.2367x; 1.2301x over previous
//
#include <hip/hip_runtime.h>

#define N_NODES 100000
#define N_EDGES 1600000
#define D 128
#define DE 16
#define G 512
#define EPSBN 1e-5f
#define ESLICE 16   // blocks per graph in k_edge_hidden (x4 waves = 64 streams/graph)
#define EPB 2048    // edges per block in k_scatter
#define EPT (EPB / 256)

typedef __bf16 bf16x8 __attribute__((ext_vector_type(8)));
typedef float f32x4 __attribute__((ext_vector_type(4)));

// ---------------- K0: init deg=1 (self loop), zero counters/accumulators ----------------
__global__ void k_init(int* __restrict__ deg, int* __restrict__ ecnt,
                       float* __restrict__ gcnt, float* __restrict__ gsum,
                       float* __restrict__ esum) {
  int i = blockIdx.x * 256 + threadIdx.x;
  if (i < N_NODES) deg[i] = 1;
  if (i < G) { ecnt[i] = 0; gcnt[i] = 0.f; }
  if (i < G * D) { gsum[i] = 0.f; esum[i] = 0.f; }
}

// ---------------- K1: count in-degree per node + edges per graph (LDS bins) ----------------
__global__ void k_count(const int* __restrict__ ei, const int* __restrict__ batch,
                        int* __restrict__ deg, int* __restrict__ ecnt) {
  __shared__ int bins[G];
  int tid = threadIdx.x;
  for (int i = tid; i < G; i += 256) bins[i] = 0;
  __syncthreads();
  int base = blockIdx.x * 4096;
  for (int t = tid; t < 4096; t += 256) {
    int e = base + t;
    if (e < N_EDGES) {
      int s = ei[e];
      int d = ei[N_EDGES + e];
      atomicAdd(&deg[d], 1);
      atomicAdd(&bins[batch[s]], 1);
    }
  }
  __syncthreads();
  for (int i = tid; i < G; i += 256) if (bins[i]) atomicAdd(&ecnt[i], bins[i]);
}

// ---------------- K2: single-block exclusive scans (node CSR starts + graph bucket starts) ----
__global__ void k_scan(const int* __restrict__ deg, int* __restrict__ rs, int* __restrict__ cursor,
                       const int* __restrict__ ecnt, int* __restrict__ ebs, int* __restrict__ ecur_pad) {
  __shared__ int sb[1024];
  int tid = threadIdx.x;
  const int chunk = (N_NODES + 1023) / 1024;  // 98
  int start = tid * chunk;
  int end = start + chunk; if (end > N_NODES) end = N_NODES;
  int s = 0;
  for (int i = start; i < end; ++i) s += deg[i];
  sb[tid] = s;
  __syncthreads();
  for (int off = 1; off < 1024; off <<= 1) {
    int t = (tid >= off) ? sb[tid - off] : 0;
    __syncthreads();
    sb[tid] += t;
    __syncthreads();
  }
  int run = sb[tid] - s;  // exclusive prefix of this chunk
  for (int i = start; i < end; ++i) { rs[i] = run; cursor[i] = run; run += deg[i]; }
  __syncthreads();
  int v2 = (tid < G) ? ecnt[tid] : 0;
  sb[tid] = v2;
  __syncthreads();
  for (int off = 1; off < 1024; off <<= 1) {
    int t = (tid >= off) ? sb[tid - off] : 0;
    __syncthreads();
    sb[tid] += t;
    __syncthreads();
  }
  if (tid < G) { ebs[tid] = sb[tid] - v2; ecur_pad[tid * 16] = sb[tid] - v2; }
}

// ---------------- K3: dinv = rsqrt(deg) ----------------
__global__ void k_dinv(const int* __restrict__ deg, float* __restrict__ dinv) {
  int i = blockIdx.x * 256 + threadIdx.x;
  if (i < N_NODES) dinv[i] = rsqrtf((float)deg[i]);
}

// ---------------- K4: scatter edges into node-CSR (atomic cursors) and graph buckets
// (block-local counting sort: LDS ranks + one padded global reservation per bin) ------------
__global__ __launch_bounds__(256) void k_scatter(const int* __restrict__ ei,
                                                 const int* __restrict__ batch,
                                                 int* __restrict__ cursor,
                                                 int* __restrict__ ecur_pad,
                                                 int* __restrict__ nbr,
                                                 int* __restrict__ ebkt) {
  __shared__ int bins[G];
  __shared__ int base[G];
  int tid = threadIdx.x;
  for (int i = tid; i < G; i += 256) bins[i] = 0;
  __syncthreads();
  int e0 = blockIdx.x * EPB;
  int ge[EPT], gr[EPT];
  #pragma unroll
  for (int k = 0; k < EPT; ++k) {
    int e = e0 + k * 256 + tid;
    ge[k] = -1;
    if (e < N_EDGES) {
      int s = ei[e], d = ei[N_EDGES + e];
      int pos = atomicAdd(&cursor[d], 1);
      nbr[pos] = s;
      int g = batch[s];
      ge[k] = g;
      gr[k] = atomicAdd(&bins[g], 1);
    }
  }
  __syncthreads();
  for (int i = tid; i < G; i += 256) {
    int cnt = bins[i];
    base[i] = cnt ? atomicAdd(&ecur_pad[i * 16], cnt) : 0;
  }
  __syncthreads();
  #pragma unroll
  for (int k = 0; k < EPT; ++k) {
    if (ge[k] >= 0) {
      int e = e0 + k * 256 + tid;
      ebkt[base[ge[k]] + gr[k]] = e;
    }
  }
}

// ---------------- K5/K7: out = (X @ W) * dinv[row]   (N x 128 @ 128 x 128, fp32) -------------
__global__ __launch_bounds__(256) void k_gemm_scale(const float* __restrict__ X,
                                                    const float* __restrict__ W,
                                                    const float* __restrict__ dinv,
                                                    float* __restrict__ out) {
  __shared__ float sX[128][32];
  __shared__ float sW[32][128];
  int tid = threadIdx.x;
  int tx = tid & 15, ty = tid >> 4;
  int rowBase = blockIdx.x * 128;
  float acc[8][8] = {};
  for (int kc = 0; kc < 128; kc += 32) {
    #pragma unroll
    for (int i = 0; i < 4; ++i) {
      int idx = tid + i * 256;          // 0..1023 -> 128 rows x 8 float4
      int r = idx >> 3, kq = idx & 7;
      int row = rowBase + r;
      float4 v = make_float4(0.f, 0.f, 0.f, 0.f);
      if (row < N_NODES) v = *(const float4*)(X + (size_t)row * 128 + kc + kq * 4);
      *(float4*)(&sX[r][kq * 4]) = v;
    }
    #pragma unroll
    for (int i = 0; i < 4; ++i) {
      int idx = tid + i * 256;          // 32 rows x 32 float4
      int k = idx >> 5, cq = idx & 31;
      *(float4*)(&sW[k][cq * 4]) = *(const float4*)(W + (size_t)(kc + k) * 128 + cq * 4);
    }
    __syncthreads();
    #pragma unroll 4
    for (int k = 0; k < 32; ++k) {
      float a[8], b[8];
      #pragma unroll
      for (int j = 0; j < 8; ++j) a[j] = sX[ty * 8 + j][k];
      *(float4*)(&b[0]) = *(float4*)(&sW[k][tx * 8]);
      *(float4*)(&b[4]) = *(float4*)(&sW[k][tx * 8 + 4]);
      #pragma unroll
      for (int j = 0; j < 8; ++j)
        #pragma unroll
        for (int c = 0; c < 8; ++c) acc[j][c] += a[j] * b[c];
    }
    __syncthreads();
  }
  #pragma unroll
  for (int j = 0; j < 8; ++j) {
    int row = rowBase + ty * 8 + j;
    if (row < N_NODES) {
      float dv = dinv[row];
      float4 o0, o1;
      o0.x = acc[j][0] * dv; o0.y = acc[j][1] * dv; o0.z = acc[j][2] * dv; o0.w = acc[j][3] * dv;
      o1.x = acc[j][4] * dv; o1.y = acc[j][5] * dv; o1.z = acc[j][6] * dv; o1.w = acc[j][7] * dv;
      *(float4*)(out + (size_t)row * 128 + tx * 8) = o0;
      *(float4*)(out + (size_t)row * 128 + tx * 8 + 4) = o1;
    }
  }
}

// ---------------- K6: CSR aggregate + bias + BN + ReLU -> out ----------------
__global__ void k_agg_bn(const float* __restrict__ A, const int* __restrict__ nbr,
                         const int* __restrict__ rs, const int* __restrict__ deg,
                         const float* __restrict__ dinv,
                         const float* __restrict__ b, const float* __restrict__ gm,
                         const float* __restrict__ bt, const float* __restrict__ m,
                         const float* __restrict__ v, float* __restrict__ out) {
  int tid = threadIdx.x;
  int c = tid & 127;
  int half = tid >> 7;
  int gid = blockIdx.x * 2 + half;  // 32 nodes per group
  if (gid * 32 >= N_NODES) return;
  float scale = gm[c] * rsqrtf(v[c] + EPSBN);
  float shift = bt[c] - m[c] * scale;
  float bias = b[c];
  int base = gid * 32;
  for (int nn = 0; nn < 32; ++nn) {
    int i = base + nn;
    float sum = A[(size_t)i * 128 + c];   // self loop (already dinv-scaled)
    int j = rs[i];
    int end = j + deg[i] - 1;             // indeg real edges
    for (; j + 3 < end; j += 4) {
      int s0 = nbr[j], s1 = nbr[j + 1], s2 = nbr[j + 2], s3 = nbr[j + 3];
      sum += A[(size_t)s0 * 128 + c];
      sum += A[(size_t)s1 * 128 + c];
      sum += A[(size_t)s2 * 128 + c];
      sum += A[(size_t)s3 * 128 + c];
    }
    for (; j < end; ++j) sum += A[(size_t)nbr[j] * 128 + c];
    float y = dinv[i] * sum + bias;
    out[(size_t)i * 128 + c] = fmaxf(y * scale + shift, 0.f);
  }
}

// ---------------- K8: CSR aggregate + BN + ReLU + sorted-batch mean-pool accumulate ----------
__global__ void k_agg_bn_pool(const float* __restrict__ A, const int* __restrict__ nbr,
                              const int* __restrict__ rs, const int* __restrict__ deg,
                              const float* __restrict__ dinv, const int* __restrict__ batch,
                              const float* __restrict__ b, const float* __restrict__ gm,
                              const float* __restrict__ bt, const float* __restrict__ m,
                              const float* __restrict__ v,
                              float* __restrict__ gsum, float* __restrict__ gcnt) {
  int tid = threadIdx.x;
  int c = tid & 127;
  int half = tid >> 7;
  int gid = blockIdx.x * 2 + half;
  if (gid * 32 >= N_NODES) return;
  float scale = gm[c] * rsqrtf(v[c] + EPSBN);
  float shift = bt[c] - m[c] * scale;
  float bias = b[c];
  int base = gid * 32;
  float acc = 0.f, cnt = 0.f;
  int curg = -1;
  for (int nn = 0; nn < 32; ++nn) {
    int i = base + nn;
    int bg = batch[i];
    if (bg != curg) {
      if (curg >= 0) {
        atomicAdd(&gsum[(size_t)curg * 128 + c], acc);
        if (c == 0) atomicAdd(&gcnt[curg], cnt);
      }
      acc = 0.f; cnt = 0.f; curg = bg;
    }
    float sum = A[(size_t)i * 128 + c];
    int j = rs[i];
    int end = j + deg[i] - 1;
    for (; j + 3 < end; j += 4) {
      int s0 = nbr[j], s1 = nbr[j + 1], s2 = nbr[j + 2], s3 = nbr[j + 3];
      sum += A[(size_t)s0 * 128 + c];
      sum += A[(size_t)s1 * 128 + c];
      sum += A[(size_t)s2 * 128 + c];
      sum += A[(size_t)s3 * 128 + c];
    }
    for (; j < end; ++j) sum += A[(size_t)nbr[j] * 128 + c];
    float y = dinv[i] * sum + bias;
    acc += fmaxf(y * scale + shift, 0.f);
    cnt += 1.f;
  }
  atomicAdd(&gsum[(size_t)curg * 128 + c], acc);
  if (c == 0) atomicAdd(&gcnt[curg], cnt);
}

// ---------------- K9: per-graph sum of relu(edge_attr @ We1 + be1) via bf16 MFMA -------------
// 4 waves/block; each wave owns a contiguous range of 16-edge tiles of graph g's bucket.
// A-frag: 16 edges x 16 feat (K=32, upper half zero). B-frag: We1 as 8 channel blocks.
// C/D layout (m89): col=lane&15, row=(lane>>4)*4+reg. A/B: k-group = lane>>4, 8 elems/lane.
__global__ __launch_bounds__(256) void k_edge_hidden(
    const float* __restrict__ edge_attr, const int* __restrict__ ebkt,
    const int* __restrict__ ebs, const int* __restrict__ ecnt,
    const float* __restrict__ We1, const float* __restrict__ be1,
    float* __restrict__ esum) {
  int tid = threadIdx.x;
  int wave = tid >> 6;
  int lane = tid & 63;
  int n = lane & 15;           // channel-within-block / edge-row index
  int kg = lane >> 4;          // k-group 0..3 (k = kg*8 + j); kg>=2 -> zero pad
  int g = blockIdx.x / ESLICE;
  int slice = blockIdx.x % ESLICE;

  // B fragments: 8 channel blocks of We1 (16 x 16), bf16
  bf16x8 bfrag[8];
  float biasv[8];
  #pragma unroll
  for (int blk = 0; blk < 8; ++blk) {
    #pragma unroll
    for (int j = 0; j < 8; ++j) {
      int k = kg * 8 + j;
      float w = (k < DE) ? We1[k * 128 + blk * 16 + n] : 0.f;
      bfrag[blk][j] = (__bf16)w;
    }
    biasv[blk] = be1[blk * 16 + n];
  }

  int start = ebs[g], cnt = ecnt[g];
  int lim = start + cnt;
  int ntiles = (cnt + 15) >> 4;
  const int nstream = ESLICE * 4;
  int sid = slice * 4 + wave;
  int tpc = (ntiles + nstream - 1) / nstream;
  int t0 = sid * tpc;
  int t1 = t0 + tpc; if (t1 > ntiles) t1 = ntiles;

  float racc[8] = {0.f, 0.f, 0.f, 0.f, 0.f, 0.f, 0.f, 0.f};

  for (int t = t0; t < t1; ++t) {
    int jb = start + (t << 4);
    // edge id for this lane's row (n = edge-in-tile); clamp for safety, mask later
    int idx = jb + n;
    int idc = idx < lim - 1 ? idx : lim - 1;
    int e = ebkt[idc];
    bf16x8 afrag = {};
    if (kg < 2) {
      const float4* p = (const float4*)(edge_attr + (size_t)e * DE + kg * 8);
      float4 f0 = p[0], f1 = p[1];
      afrag[0] = (__bf16)f0.x; afrag[1] = (__bf16)f0.y;
      afrag[2] = (__bf16)f0.z; afrag[3] = (__bf16)f0.w;
      afrag[4] = (__bf16)f1.x; afrag[5] = (__bf16)f1.y;
      afrag[6] = (__bf16)f1.z; afrag[7] = (__bf16)f1.w;
    }
    bool full = (jb + 16 <= lim);   // wave-uniform
    if (full) {
      #pragma unroll
      for (int blk = 0; blk < 8; ++blk) {
        f32x4 acc = {0.f, 0.f, 0.f, 0.f};
        acc = __builtin_amdgcn_mfma_f32_16x16x32_bf16(afrag, bfrag[blk], acc, 0, 0, 0);
        #pragma unroll
        for (int r = 0; r < 4; ++r)
          racc[blk] += fmaxf(acc[r] + biasv[blk], 0.f);
      }
    } else {
      #pragma unroll
      for (int blk = 0; blk < 8; ++blk) {
        f32x4 acc = {0.f, 0.f, 0.f, 0.f};
        acc = __builtin_amdgcn_mfma_f32_16x16x32_bf16(afrag, bfrag[blk], acc, 0, 0, 0);
        #pragma unroll
        for (int r = 0; r < 4; ++r) {
          int row = kg * 4 + r;
          if (jb + row < lim) racc[blk] += fmaxf(acc[r] + biasv[blk], 0.f);
        }
      }
    }
  }

  // reduce across the 4 row-groups (lanes n, n+16, n+32, n+48 hold channel blk*16+n)
  #pragma unroll
  for (int blk = 0; blk < 8; ++blk) {
    float vsum = racc[blk];
    vsum += __shfl_xor(vsum, 16);
    vsum += __shfl_xor(vsum, 32);
    if (lane < 16) atomicAdd(&esum[(size_t)g * 128 + blk * 16 + n], vsum);
  }
}

// ---------------- K10: graph mean + (edge mean hidden) @ We2 + be2 -> out ----------------
__global__ void k_final(const float* __restrict__ esum, const int* __restrict__ ecnt,
                        const float* __restrict__ gsum, const float* __restrict__ gcnt,
                        const float* __restrict__ We2, const float* __restrict__ be2,
                        float* __restrict__ out) {
  __shared__ float mh[128];
  int g = blockIdx.x, c = threadIdx.x;
  int ec = ecnt[g];
  mh[c] = (ec > 0) ? esum[(size_t)g * 128 + c] / (float)ec : 0.f;
  __syncthreads();
  float acc = 0.f;
  #pragma unroll 8
  for (int k = 0; k < 128; ++k) acc += mh[k] * We2[k * 128 + c];
  float er = (ec > 0) ? (acc + be2[c]) : 0.f;
  float gr = gsum[(size_t)g * 128 + c] / fmaxf(gcnt[g], 1.f);
  out[(size_t)g * 128 + c] = gr + er;
}

extern "C" void kernel_launch(void* const* d_in, const int* in_sizes, int n_in,
                              void* d_out, int out_size, void* d_ws, size_t ws_size,
                              hipStream_t stream) {
  const float* x        = (const float*)d_in[0];
  const int*   ei       = (const int*)d_in[1];     // [2, E]
  const int*   batch    = (const int*)d_in[2];     // [N], sorted
  const float* edge_attr= (const float*)d_in[3];   // [E, 16]
  const float* W1 = (const float*)d_in[5];
  const float* b1 = (const float*)d_in[6];
  const float* g1 = (const float*)d_in[7];
  const float* bt1= (const float*)d_in[8];
  const float* m1 = (const float*)d_in[9];
  const float* v1 = (const float*)d_in[10];
  const float* W2 = (const float*)d_in[11];
  const float* b2 = (const float*)d_in[12];
  const float* g2 = (const float*)d_in[13];
  const float* bt2= (const float*)d_in[14];
  const float* m2 = (const float*)d_in[15];
  const float* v2 = (const float*)d_in[16];
  const float* We1= (const float*)d_in[17];
  const float* be1= (const float*)d_in[18];
  const float* We2= (const float*)d_in[19];
  const float* be2= (const float*)d_in[20];
  float* out = (float*)d_out;

  char* ws = (char*)d_ws;
  size_t off = 0;
  auto take = [&](size_t bytes) -> char* {
    char* p = ws + off;
    off += (bytes + 255) & ~(size_t)255;
    return p;
  };
  float* A       = (float*)take((size_t)N_NODES * 128 * 4);
  float* B       = (float*)take((size_t)N_NODES * 128 * 4);
  float* dinv    = (float*)take((size_t)N_NODES * 4);
  int*   deg     = (int*)  take((size_t)N_NODES * 4);
  int*   rs      = (int*)  take((size_t)N_NODES * 4);
  int*   cursor  = (int*)  take((size_t)N_NODES * 4);
  int*   nbr     = (int*)  take((size_t)(N_EDGES + N_NODES) * 4);
  int*   ebkt    = (int*)  take((size_t)N_EDGES * 4);
  int*   ecnt    = (int*)  take((size_t)G * 4);
  int*   ebs     = (int*)  take((size_t)G * 4);
  int*   ecur_pad= (int*)  take((size_t)G * 16 * 4);  // 64B-stride cursors
  float* gcnt    = (float*)take((size_t)G * 4);
  float* esum    = (float*)take((size_t)G * 128 * 4);
  float* gsum    = (float*)take((size_t)G * 128 * 4);

  k_init<<<(N_NODES + 255) / 256, 256, 0, stream>>>(deg, ecnt, gcnt, gsum, esum);
  k_count<<<(N_EDGES + 4095) / 4096, 256, 0, stream>>>(ei, batch, deg, ecnt);
  k_scan<<<1, 1024, 0, stream>>>(deg, rs, cursor, ecnt, ebs, ecur_pad);
  k_dinv<<<(N_NODES + 255) / 256, 256, 0, stream>>>(deg, dinv);
  k_scatter<<<(N_EDGES + EPB - 1) / EPB, 256, 0, stream>>>(ei, batch, cursor, ecur_pad, nbr, ebkt);
  // layer 1
  k_gemm_scale<<<(N_NODES + 127) / 128, 256, 0, stream>>>(x, W1, dinv, A);
  k_agg_bn<<<(N_NODES / 32 + 1) / 2 + 1, 256, 0, stream>>>(A, nbr, rs, deg, dinv, b1, g1, bt1, m1, v1, B);
  // layer 2 (+ pooling fused)
  k_gemm_scale<<<(N_NODES + 127) / 128, 256, 0, stream>>>(B, W2, dinv, A);
  k_agg_bn_pool<<<(N_NODES / 32 + 1) / 2 + 1, 256, 0, stream>>>(A, nbr, rs, deg, dinv, batch, b2, g2, bt2, m2, v2, gsum, gcnt);
  // edge path
  k_edge_hidden<<<G * ESLICE, 256, 0, stream>>>(edge_attr, ebkt, ebs, ecnt, We1, be1, esum);
  k_final<<<G, 128, 0, stream>>>(esum, ecnt, gsum, gcnt, We2, be2, out);
}

// Round 5
// 1017.139 us; speedup vs baseline: 2.6852x; 1.2005x over previous
//
#include <hip/hip_runtime.h>

#define N_NODES 100000
#define N_EDGES 1600000
#define D 128
#define DE 16
#define G 512
#define EPSBN 1e-5f
#define ESLICE 16   // blocks per graph in k_edge_hidden (x4 waves = 64 streams/graph)
#define EPB 2048    // edges per block in k_scatter
#define EPT (EPB / 256)
#define SCHUNK 1024 // nodes per block in hierarchical scan
#define NSB ((N_NODES + SCHUNK - 1) / SCHUNK)  // 98

typedef __bf16 bf16x8 __attribute__((ext_vector_type(8)));
typedef float f32x4 __attribute__((ext_vector_type(4)));

// ---------------- K0: init deg=1 (self loop), zero counters/accumulators ----------------
__global__ void k_init(int* __restrict__ deg, int* __restrict__ ecnt,
                       float* __restrict__ gcnt, float* __restrict__ gsum,
                       float* __restrict__ esum) {
  int i = blockIdx.x * 256 + threadIdx.x;
  if (i < N_NODES) deg[i] = 1;
  if (i < G) { ecnt[i] = 0; gcnt[i] = 0.f; }
  if (i < G * D) { gsum[i] = 0.f; esum[i] = 0.f; }
}

// ---------------- K1: count in-degree per node + edges per graph (LDS bins) ----------------
__global__ void k_count(const int* __restrict__ ei, const int* __restrict__ batch,
                        int* __restrict__ deg, int* __restrict__ ecnt) {
  __shared__ int bins[G];
  int tid = threadIdx.x;
  for (int i = tid; i < G; i += 256) bins[i] = 0;
  __syncthreads();
  int base = blockIdx.x * 4096;
  for (int t = tid; t < 4096; t += 256) {
    int e = base + t;
    if (e < N_EDGES) {
      int s = ei[e];
      int d = ei[N_EDGES + e];
      atomicAdd(&deg[d], 1);
      atomicAdd(&bins[batch[s]], 1);
    }
  }
  __syncthreads();
  for (int i = tid; i < G; i += 256) if (bins[i]) atomicAdd(&ecnt[i], bins[i]);
}

// ---------------- K2a: per-block partial sums of deg ----------------
__global__ __launch_bounds__(256) void k_scan_part(const int* __restrict__ deg,
                                                   int* __restrict__ part) {
  __shared__ int red[4];
  int tid = threadIdx.x;
  int base = blockIdx.x * SCHUNK + tid * 4;
  int s = 0;
  #pragma unroll
  for (int k = 0; k < 4; ++k) {
    int i = base + k;
    if (i < N_NODES) s += deg[i];
  }
  #pragma unroll
  for (int off = 32; off > 0; off >>= 1) s += __shfl_down(s, off);
  if ((tid & 63) == 0) red[tid >> 6] = s;
  __syncthreads();
  if (tid == 0) part[blockIdx.x] = red[0] + red[1] + red[2] + red[3];
}

// ---------------- K2b: single block: scan 98 partials + scan 512 ecnt ----------------
__global__ void k_scan_mid(int* __restrict__ part, const int* __restrict__ ecnt,
                           int* __restrict__ ebs, int* __restrict__ ecur_pad) {
  __shared__ int sb[512];
  int tid = threadIdx.x;  // 512 threads
  int v = (tid < NSB) ? part[tid] : 0;
  sb[tid] = v;
  __syncthreads();
  for (int off = 1; off < 512; off <<= 1) {
    int t = (tid >= off) ? sb[tid - off] : 0;
    __syncthreads();
    sb[tid] += t;
    __syncthreads();
  }
  if (tid < NSB) part[tid] = sb[tid] - v;  // exclusive block bases
  __syncthreads();
  int v2 = ecnt[tid];  // G == 512 == blockDim
  sb[tid] = v2;
  __syncthreads();
  for (int off = 1; off < 512; off <<= 1) {
    int t = (tid >= off) ? sb[tid - off] : 0;
    __syncthreads();
    sb[tid] += t;
    __syncthreads();
  }
  ebs[tid] = sb[tid] - v2;
  ecur_pad[tid * 16] = sb[tid] - v2;
}

// ---------------- K2c: write rs/cursor (exclusive prefix) + dinv ----------------
__global__ __launch_bounds__(256) void k_scan_write(const int* __restrict__ deg,
                                                    const int* __restrict__ part,
                                                    int* __restrict__ rs,
                                                    int* __restrict__ cursor,
                                                    float* __restrict__ dinv) {
  __shared__ int sb[256];
  int tid = threadIdx.x;
  int base = blockIdx.x * SCHUNK + tid * 4;
  int d[4];
  int s = 0;
  #pragma unroll
  for (int k = 0; k < 4; ++k) {
    int i = base + k;
    d[k] = (i < N_NODES) ? deg[i] : 0;
    s += d[k];
  }
  sb[tid] = s;
  __syncthreads();
  for (int off = 1; off < 256; off <<= 1) {
    int t = (tid >= off) ? sb[tid - off] : 0;
    __syncthreads();
    sb[tid] += t;
    __syncthreads();
  }
  int ex = sb[tid] - s + part[blockIdx.x];
  #pragma unroll
  for (int k = 0; k < 4; ++k) {
    int i = base + k;
    if (i < N_NODES) {
      rs[i] = ex;
      cursor[i] = ex;
      dinv[i] = rsqrtf((float)d[k]);
      ex += d[k];
    }
  }
}

// ---------------- K4: scatter edges into node-CSR (atomic cursors) and graph buckets
// (block-local counting sort: LDS ranks + one padded global reservation per bin) ------------
__global__ __launch_bounds__(256) void k_scatter(const int* __restrict__ ei,
                                                 const int* __restrict__ batch,
                                                 int* __restrict__ cursor,
                                                 int* __restrict__ ecur_pad,
                                                 int* __restrict__ nbr,
                                                 int* __restrict__ ebkt) {
  __shared__ int bins[G];
  __shared__ int base[G];
  int tid = threadIdx.x;
  for (int i = tid; i < G; i += 256) bins[i] = 0;
  __syncthreads();
  int e0 = blockIdx.x * EPB;
  int ge[EPT], gr[EPT];
  #pragma unroll
  for (int k = 0; k < EPT; ++k) {
    int e = e0 + k * 256 + tid;
    ge[k] = -1;
    if (e < N_EDGES) {
      int s = ei[e], d = ei[N_EDGES + e];
      int pos = atomicAdd(&cursor[d], 1);
      nbr[pos] = s;
      int g = batch[s];
      ge[k] = g;
      gr[k] = atomicAdd(&bins[g], 1);
    }
  }
  __syncthreads();
  for (int i = tid; i < G; i += 256) {
    int cnt = bins[i];
    base[i] = cnt ? atomicAdd(&ecur_pad[i * 16], cnt) : 0;
  }
  __syncthreads();
  #pragma unroll
  for (int k = 0; k < EPT; ++k) {
    if (ge[k] >= 0) {
      int e = e0 + k * 256 + tid;
      ebkt[base[ge[k]] + gr[k]] = e;
    }
  }
}

// ---------------- K5/K7: out = (X @ W) * dinv[row]   (N x 128 @ 128 x 128, fp32) -------------
__global__ __launch_bounds__(256) void k_gemm_scale(const float* __restrict__ X,
                                                    const float* __restrict__ W,
                                                    const float* __restrict__ dinv,
                                                    float* __restrict__ out) {
  __shared__ float sX[128][32];
  __shared__ float sW[32][128];
  int tid = threadIdx.x;
  int tx = tid & 15, ty = tid >> 4;
  int rowBase = blockIdx.x * 128;
  float acc[8][8] = {};
  for (int kc = 0; kc < 128; kc += 32) {
    #pragma unroll
    for (int i = 0; i < 4; ++i) {
      int idx = tid + i * 256;          // 0..1023 -> 128 rows x 8 float4
      int r = idx >> 3, kq = idx & 7;
      int row = rowBase + r;
      float4 v = make_float4(0.f, 0.f, 0.f, 0.f);
      if (row < N_NODES) v = *(const float4*)(X + (size_t)row * 128 + kc + kq * 4);
      *(float4*)(&sX[r][kq * 4]) = v;
    }
    #pragma unroll
    for (int i = 0; i < 4; ++i) {
      int idx = tid + i * 256;          // 32 rows x 32 float4
      int k = idx >> 5, cq = idx & 31;
      *(float4*)(&sW[k][cq * 4]) = *(const float4*)(W + (size_t)(kc + k) * 128 + cq * 4);
    }
    __syncthreads();
    #pragma unroll 4
    for (int k = 0; k < 32; ++k) {
      float a[8], b[8];
      #pragma unroll
      for (int j = 0; j < 8; ++j) a[j] = sX[ty * 8 + j][k];
      *(float4*)(&b[0]) = *(float4*)(&sW[k][tx * 8]);
      *(float4*)(&b[4]) = *(float4*)(&sW[k][tx * 8 + 4]);
      #pragma unroll
      for (int j = 0; j < 8; ++j)
        #pragma unroll
        for (int c = 0; c < 8; ++c) acc[j][c] += a[j] * b[c];
    }
    __syncthreads();
  }
  #pragma unroll
  for (int j = 0; j < 8; ++j) {
    int row = rowBase + ty * 8 + j;
    if (row < N_NODES) {
      float dv = dinv[row];
      float4 o0, o1;
      o0.x = acc[j][0] * dv; o0.y = acc[j][1] * dv; o0.z = acc[j][2] * dv; o0.w = acc[j][3] * dv;
      o1.x = acc[j][4] * dv; o1.y = acc[j][5] * dv; o1.z = acc[j][6] * dv; o1.w = acc[j][7] * dv;
      *(float4*)(out + (size_t)row * 128 + tx * 8) = o0;
      *(float4*)(out + (size_t)row * 128 + tx * 8 + 4) = o1;
    }
  }
}

// ---------------- K6: CSR aggregate + bias + BN + ReLU -> out ----------------
__global__ void k_agg_bn(const float* __restrict__ A, const int* __restrict__ nbr,
                         const int* __restrict__ rs, const int* __restrict__ deg,
                         const float* __restrict__ dinv,
                         const float* __restrict__ b, const float* __restrict__ gm,
                         const float* __restrict__ bt, const float* __restrict__ m,
                         const float* __restrict__ v, float* __restrict__ out) {
  int tid = threadIdx.x;
  int c = tid & 127;
  int half = tid >> 7;
  int gid = blockIdx.x * 2 + half;  // 32 nodes per group
  if (gid * 32 >= N_NODES) return;
  float scale = gm[c] * rsqrtf(v[c] + EPSBN);
  float shift = bt[c] - m[c] * scale;
  float bias = b[c];
  int base = gid * 32;
  for (int nn = 0; nn < 32; ++nn) {
    int i = base + nn;
    float sum = A[(size_t)i * 128 + c];   // self loop (already dinv-scaled)
    int j = rs[i];
    int end = j + deg[i] - 1;             // indeg real edges
    for (; j + 3 < end; j += 4) {
      int s0 = nbr[j], s1 = nbr[j + 1], s2 = nbr[j + 2], s3 = nbr[j + 3];
      sum += A[(size_t)s0 * 128 + c];
      sum += A[(size_t)s1 * 128 + c];
      sum += A[(size_t)s2 * 128 + c];
      sum += A[(size_t)s3 * 128 + c];
    }
    for (; j < end; ++j) sum += A[(size_t)nbr[j] * 128 + c];
    float y = dinv[i] * sum + bias;
    out[(size_t)i * 128 + c] = fmaxf(y * scale + shift, 0.f);
  }
}

// ---------------- K8: CSR aggregate + BN + ReLU + sorted-batch mean-pool accumulate ----------
__global__ void k_agg_bn_pool(const float* __restrict__ A, const int* __restrict__ nbr,
                              const int* __restrict__ rs, const int* __restrict__ deg,
                              const float* __restrict__ dinv, const int* __restrict__ batch,
                              const float* __restrict__ b, const float* __restrict__ gm,
                              const float* __restrict__ bt, const float* __restrict__ m,
                              const float* __restrict__ v,
                              float* __restrict__ gsum, float* __restrict__ gcnt) {
  int tid = threadIdx.x;
  int c = tid & 127;
  int half = tid >> 7;
  int gid = blockIdx.x * 2 + half;
  if (gid * 32 >= N_NODES) return;
  float scale = gm[c] * rsqrtf(v[c] + EPSBN);
  float shift = bt[c] - m[c] * scale;
  float bias = b[c];
  int base = gid * 32;
  float acc = 0.f, cnt = 0.f;
  int curg = -1;
  for (int nn = 0; nn < 32; ++nn) {
    int i = base + nn;
    int bg = batch[i];
    if (bg != curg) {
      if (curg >= 0) {
        atomicAdd(&gsum[(size_t)curg * 128 + c], acc);
        if (c == 0) atomicAdd(&gcnt[curg], cnt);
      }
      acc = 0.f; cnt = 0.f; curg = bg;
    }
    float sum = A[(size_t)i * 128 + c];
    int j = rs[i];
    int end = j + deg[i] - 1;
    for (; j + 3 < end; j += 4) {
      int s0 = nbr[j], s1 = nbr[j + 1], s2 = nbr[j + 2], s3 = nbr[j + 3];
      sum += A[(size_t)s0 * 128 + c];
      sum += A[(size_t)s1 * 128 + c];
      sum += A[(size_t)s2 * 128 + c];
      sum += A[(size_t)s3 * 128 + c];
    }
    for (; j < end; ++j) sum += A[(size_t)nbr[j] * 128 + c];
    float y = dinv[i] * sum + bias;
    acc += fmaxf(y * scale + shift, 0.f);
    cnt += 1.f;
  }
  atomicAdd(&gsum[(size_t)curg * 128 + c], acc);
  if (c == 0) atomicAdd(&gcnt[curg], cnt);
}

// ---------------- K9: per-graph sum of relu(edge_attr @ We1 + be1) via bf16 MFMA -------------
__global__ __launch_bounds__(256) void k_edge_hidden(
    const float* __restrict__ edge_attr, const int* __restrict__ ebkt,
    const int* __restrict__ ebs, const int* __restrict__ ecnt,
    const float* __restrict__ We1, const float* __restrict__ be1,
    float* __restrict__ esum) {
  int tid = threadIdx.x;
  int wave = tid >> 6;
  int lane = tid & 63;
  int n = lane & 15;           // channel-within-block / edge-row index
  int kg = lane >> 4;          // k-group 0..3 (k = kg*8 + j); kg>=2 -> zero pad
  int g = blockIdx.x / ESLICE;
  int slice = blockIdx.x % ESLICE;

  bf16x8 bfrag[8];
  float biasv[8];
  #pragma unroll
  for (int blk = 0; blk < 8; ++blk) {
    #pragma unroll
    for (int j = 0; j < 8; ++j) {
      int k = kg * 8 + j;
      float w = (k < DE) ? We1[k * 128 + blk * 16 + n] : 0.f;
      bfrag[blk][j] = (__bf16)w;
    }
    biasv[blk] = be1[blk * 16 + n];
  }

  int start = ebs[g], cnt = ecnt[g];
  int lim = start + cnt;
  int ntiles = (cnt + 15) >> 4;
  const int nstream = ESLICE * 4;
  int sid = slice * 4 + wave;
  int tpc = (ntiles + nstream - 1) / nstream;
  int t0 = sid * tpc;
  int t1 = t0 + tpc; if (t1 > ntiles) t1 = ntiles;

  float racc[8] = {0.f, 0.f, 0.f, 0.f, 0.f, 0.f, 0.f, 0.f};

  for (int t = t0; t < t1; ++t) {
    int jb = start + (t << 4);
    int idx = jb + n;
    int idc = idx < lim - 1 ? idx : lim - 1;
    int e = ebkt[idc];
    bf16x8 afrag = {};
    if (kg < 2) {
      const float4* p = (const float4*)(edge_attr + (size_t)e * DE + kg * 8);
      float4 f0 = p[0], f1 = p[1];
      afrag[0] = (__bf16)f0.x; afrag[1] = (__bf16)f0.y;
      afrag[2] = (__bf16)f0.z; afrag[3] = (__bf16)f0.w;
      afrag[4] = (__bf16)f1.x; afrag[5] = (__bf16)f1.y;
      afrag[6] = (__bf16)f1.z; afrag[7] = (__bf16)f1.w;
    }
    bool full = (jb + 16 <= lim);   // wave-uniform
    if (full) {
      #pragma unroll
      for (int blk = 0; blk < 8; ++blk) {
        f32x4 acc = {0.f, 0.f, 0.f, 0.f};
        acc = __builtin_amdgcn_mfma_f32_16x16x32_bf16(afrag, bfrag[blk], acc, 0, 0, 0);
        #pragma unroll
        for (int r = 0; r < 4; ++r)
          racc[blk] += fmaxf(acc[r] + biasv[blk], 0.f);
      }
    } else {
      #pragma unroll
      for (int blk = 0; blk < 8; ++blk) {
        f32x4 acc = {0.f, 0.f, 0.f, 0.f};
        acc = __builtin_amdgcn_mfma_f32_16x16x32_bf16(afrag, bfrag[blk], acc, 0, 0, 0);
        #pragma unroll
        for (int r = 0; r < 4; ++r) {
          int row = kg * 4 + r;
          if (jb + row < lim) racc[blk] += fmaxf(acc[r] + biasv[blk], 0.f);
        }
      }
    }
  }

  #pragma unroll
  for (int blk = 0; blk < 8; ++blk) {
    float vsum = racc[blk];
    vsum += __shfl_xor(vsum, 16);
    vsum += __shfl_xor(vsum, 32);
    if (lane < 16) atomicAdd(&esum[(size_t)g * 128 + blk * 16 + n], vsum);
  }
}

// ---------------- K10: graph mean + (edge mean hidden) @ We2 + be2 -> out ----------------
__global__ void k_final(const float* __restrict__ esum, const int* __restrict__ ecnt,
                        const float* __restrict__ gsum, const float* __restrict__ gcnt,
                        const float* __restrict__ We2, const float* __restrict__ be2,
                        float* __restrict__ out) {
  __shared__ float mh[128];
  int g = blockIdx.x, c = threadIdx.x;
  int ec = ecnt[g];
  mh[c] = (ec > 0) ? esum[(size_t)g * 128 + c] / (float)ec : 0.f;
  __syncthreads();
  float acc = 0.f;
  #pragma unroll 8
  for (int k = 0; k < 128; ++k) acc += mh[k] * We2[k * 128 + c];
  float er = (ec > 0) ? (acc + be2[c]) : 0.f;
  float gr = gsum[(size_t)g * 128 + c] / fmaxf(gcnt[g], 1.f);
  out[(size_t)g * 128 + c] = gr + er;
}

extern "C" void kernel_launch(void* const* d_in, const int* in_sizes, int n_in,
                              void* d_out, int out_size, void* d_ws, size_t ws_size,
                              hipStream_t stream) {
  const float* x        = (const float*)d_in[0];
  const int*   ei       = (const int*)d_in[1];     // [2, E]
  const int*   batch    = (const int*)d_in[2];     // [N], sorted
  const float* edge_attr= (const float*)d_in[3];   // [E, 16]
  const float* W1 = (const float*)d_in[5];
  const float* b1 = (const float*)d_in[6];
  const float* g1 = (const float*)d_in[7];
  const float* bt1= (const float*)d_in[8];
  const float* m1 = (const float*)d_in[9];
  const float* v1 = (const float*)d_in[10];
  const float* W2 = (const float*)d_in[11];
  const float* b2 = (const float*)d_in[12];
  const float* g2 = (const float*)d_in[13];
  const float* bt2= (const float*)d_in[14];
  const float* m2 = (const float*)d_in[15];
  const float* v2 = (const float*)d_in[16];
  const float* We1= (const float*)d_in[17];
  const float* be1= (const float*)d_in[18];
  const float* We2= (const float*)d_in[19];
  const float* be2= (const float*)d_in[20];
  float* out = (float*)d_out;

  char* ws = (char*)d_ws;
  size_t off = 0;
  auto take = [&](size_t bytes) -> char* {
    char* p = ws + off;
    off += (bytes + 255) & ~(size_t)255;
    return p;
  };
  float* A       = (float*)take((size_t)N_NODES * 128 * 4);
  float* B       = (float*)take((size_t)N_NODES * 128 * 4);
  float* dinv    = (float*)take((size_t)N_NODES * 4);
  int*   deg     = (int*)  take((size_t)N_NODES * 4);
  int*   rs      = (int*)  take((size_t)N_NODES * 4);
  int*   cursor  = (int*)  take((size_t)N_NODES * 4);
  int*   nbr     = (int*)  take((size_t)(N_EDGES + N_NODES) * 4);
  int*   ebkt    = (int*)  take((size_t)N_EDGES * 4);
  int*   ecnt    = (int*)  take((size_t)G * 4);
  int*   ebs     = (int*)  take((size_t)G * 4);
  int*   ecur_pad= (int*)  take((size_t)G * 16 * 4);  // 64B-stride cursors
  float* gcnt    = (float*)take((size_t)G * 4);
  float* esum    = (float*)take((size_t)G * 128 * 4);
  float* gsum    = (float*)take((size_t)G * 128 * 4);
  int*   part    = (int*)  take((size_t)NSB * 4);

  k_init<<<(N_NODES + 255) / 256, 256, 0, stream>>>(deg, ecnt, gcnt, gsum, esum);
  k_count<<<(N_EDGES + 4095) / 4096, 256, 0, stream>>>(ei, batch, deg, ecnt);
  // hierarchical scan (+ dinv folded into the write phase)
  k_scan_part<<<NSB, 256, 0, stream>>>(deg, part);
  k_scan_mid<<<1, 512, 0, stream>>>(part, ecnt, ebs, ecur_pad);
  k_scan_write<<<NSB, 256, 0, stream>>>(deg, part, rs, cursor, dinv);
  k_scatter<<<(N_EDGES + EPB - 1) / EPB, 256, 0, stream>>>(ei, batch, cursor, ecur_pad, nbr, ebkt);
  // layer 1
  k_gemm_scale<<<(N_NODES + 127) / 128, 256, 0, stream>>>(x, W1, dinv, A);
  k_agg_bn<<<(N_NODES / 32 + 1) / 2 + 1, 256, 0, stream>>>(A, nbr, rs, deg, dinv, b1, g1, bt1, m1, v1, B);
  // layer 2 (+ pooling fused)
  k_gemm_scale<<<(N_NODES + 127) / 128, 256, 0, stream>>>(B, W2, dinv, A);
  k_agg_bn_pool<<<(N_NODES / 32 + 1) / 2 + 1, 256, 0, stream>>>(A, nbr, rs, deg, dinv, batch, b2, g2, bt2, m2, v2, gsum, gcnt);
  // edge path
  k_edge_hidden<<<G * ESLICE, 256, 0, stream>>>(edge_attr, ebkt, ebs, ecnt, We1, be1, esum);
  k_final<<<G, 128, 0, stream>>>(esum, ecnt, gsum, gcnt, We2, be2, out);
}

// Round 6
// 1003.375 us; speedup vs baseline: 2.7220x; 1.0137x over previous
//
#include <hip/hip_runtime.h>

#define N_NODES 100000
#define N_EDGES 1600000
#define D 128
#define DE 16
#define G 512
#define EPSBN 1e-5f
#define ESLICE 4    // blocks per graph in k_edge_hidden (x4 waves = 16 streams/graph)
#define EPB 2048    // edges per block in k_scatter
#define EPT (EPB / 256)
#define SCHUNK 1024 // nodes per block in hierarchical scan
#define NSB ((N_NODES + SCHUNK - 1) / SCHUNK)  // 98

typedef __bf16 bf16x8 __attribute__((ext_vector_type(8)));
typedef float f32x4 __attribute__((ext_vector_type(4)));

// ---------------- K0: init deg=1 (self loop), zero counters/accumulators ----------------
__global__ void k_init(int* __restrict__ deg, int* __restrict__ ecnt,
                       float* __restrict__ gcnt, float* __restrict__ gsum,
                       float* __restrict__ esum) {
  int i = blockIdx.x * 256 + threadIdx.x;
  if (i < N_NODES) deg[i] = 1;
  if (i < G) { ecnt[i] = 0; gcnt[i] = 0.f; }
  if (i < G * D) { gsum[i] = 0.f; esum[i] = 0.f; }
}

// ---------------- K1: count in-degree per node + edges per graph (LDS bins) ----------------
__global__ void k_count(const int* __restrict__ ei, const int* __restrict__ batch,
                        int* __restrict__ deg, int* __restrict__ ecnt) {
  __shared__ int bins[G];
  int tid = threadIdx.x;
  for (int i = tid; i < G; i += 256) bins[i] = 0;
  __syncthreads();
  int base = blockIdx.x * 4096;
  for (int t = tid; t < 4096; t += 256) {
    int e = base + t;
    if (e < N_EDGES) {
      int s = ei[e];
      int d = ei[N_EDGES + e];
      atomicAdd(&deg[d], 1);
      atomicAdd(&bins[batch[s]], 1);
    }
  }
  __syncthreads();
  for (int i = tid; i < G; i += 256) if (bins[i]) atomicAdd(&ecnt[i], bins[i]);
}

// ---------------- K2a: per-block partial sums of deg ----------------
__global__ __launch_bounds__(256) void k_scan_part(const int* __restrict__ deg,
                                                   int* __restrict__ part) {
  __shared__ int red[4];
  int tid = threadIdx.x;
  int base = blockIdx.x * SCHUNK + tid * 4;
  int s = 0;
  #pragma unroll
  for (int k = 0; k < 4; ++k) {
    int i = base + k;
    if (i < N_NODES) s += deg[i];
  }
  #pragma unroll
  for (int off = 32; off > 0; off >>= 1) s += __shfl_down(s, off);
  if ((tid & 63) == 0) red[tid >> 6] = s;
  __syncthreads();
  if (tid == 0) part[blockIdx.x] = red[0] + red[1] + red[2] + red[3];
}

// ---------------- K2b: single block: scan 98 partials + scan 512 ecnt ----------------
__global__ void k_scan_mid(int* __restrict__ part, const int* __restrict__ ecnt,
                           int* __restrict__ ebs, int* __restrict__ ecur_pad) {
  __shared__ int sb[512];
  int tid = threadIdx.x;  // 512 threads
  int v = (tid < NSB) ? part[tid] : 0;
  sb[tid] = v;
  __syncthreads();
  for (int off = 1; off < 512; off <<= 1) {
    int t = (tid >= off) ? sb[tid - off] : 0;
    __syncthreads();
    sb[tid] += t;
    __syncthreads();
  }
  if (tid < NSB) part[tid] = sb[tid] - v;  // exclusive block bases
  __syncthreads();
  int v2 = ecnt[tid];  // G == 512 == blockDim
  sb[tid] = v2;
  __syncthreads();
  for (int off = 1; off < 512; off <<= 1) {
    int t = (tid >= off) ? sb[tid - off] : 0;
    __syncthreads();
    sb[tid] += t;
    __syncthreads();
  }
  ebs[tid] = sb[tid] - v2;
  ecur_pad[tid * 16] = sb[tid] - v2;
}

// ---------------- K2c: write rs/cursor (exclusive prefix) + dinv ----------------
__global__ __launch_bounds__(256) void k_scan_write(const int* __restrict__ deg,
                                                    const int* __restrict__ part,
                                                    int* __restrict__ rs,
                                                    int* __restrict__ cursor,
                                                    float* __restrict__ dinv) {
  __shared__ int sb[256];
  int tid = threadIdx.x;
  int base = blockIdx.x * SCHUNK + tid * 4;
  int d[4];
  int s = 0;
  #pragma unroll
  for (int k = 0; k < 4; ++k) {
    int i = base + k;
    d[k] = (i < N_NODES) ? deg[i] : 0;
    s += d[k];
  }
  sb[tid] = s;
  __syncthreads();
  for (int off = 1; off < 256; off <<= 1) {
    int t = (tid >= off) ? sb[tid - off] : 0;
    __syncthreads();
    sb[tid] += t;
    __syncthreads();
  }
  int ex = sb[tid] - s + part[blockIdx.x];
  #pragma unroll
  for (int k = 0; k < 4; ++k) {
    int i = base + k;
    if (i < N_NODES) {
      rs[i] = ex;
      cursor[i] = ex;
      dinv[i] = rsqrtf((float)d[k]);
      ex += d[k];
    }
  }
}

// ---------------- K4: scatter edges into node-CSR (atomic cursors) and bf16 edge features
// into graph-sorted order (block-local counting sort + direct 32B feature copy) --------------
__global__ __launch_bounds__(256) void k_scatter(const int* __restrict__ ei,
                                                 const int* __restrict__ batch,
                                                 const float* __restrict__ edge_attr,
                                                 int* __restrict__ cursor,
                                                 int* __restrict__ ecur_pad,
                                                 int* __restrict__ nbr,
                                                 __bf16* __restrict__ eaS) {
  __shared__ int bins[G];
  __shared__ int base[G];
  int tid = threadIdx.x;
  for (int i = tid; i < G; i += 256) bins[i] = 0;
  __syncthreads();
  int e0 = blockIdx.x * EPB;
  int ge[EPT], gr[EPT];
  #pragma unroll
  for (int k = 0; k < EPT; ++k) {
    int e = e0 + k * 256 + tid;
    ge[k] = -1;
    if (e < N_EDGES) {
      int s = ei[e], d = ei[N_EDGES + e];
      int pos = atomicAdd(&cursor[d], 1);
      nbr[pos] = s;
      int g = batch[s];
      ge[k] = g;
      gr[k] = atomicAdd(&bins[g], 1);
    }
  }
  __syncthreads();
  for (int i = tid; i < G; i += 256) {
    int cnt = bins[i];
    base[i] = cnt ? atomicAdd(&ecur_pad[i * 16], cnt) : 0;
  }
  __syncthreads();
  #pragma unroll
  for (int k = 0; k < EPT; ++k) {
    if (ge[k] >= 0) {
      int e = e0 + k * 256 + tid;
      int pos = base[ge[k]] + gr[k];
      const float4* p = (const float4*)(edge_attr + (size_t)e * DE);
      float4 f0 = p[0], f1 = p[1], f2 = p[2], f3 = p[3];
      bf16x8 h0, h1;
      h0[0] = (__bf16)f0.x; h0[1] = (__bf16)f0.y; h0[2] = (__bf16)f0.z; h0[3] = (__bf16)f0.w;
      h0[4] = (__bf16)f1.x; h0[5] = (__bf16)f1.y; h0[6] = (__bf16)f1.z; h0[7] = (__bf16)f1.w;
      h1[0] = (__bf16)f2.x; h1[1] = (__bf16)f2.y; h1[2] = (__bf16)f2.z; h1[3] = (__bf16)f2.w;
      h1[4] = (__bf16)f3.x; h1[5] = (__bf16)f3.y; h1[6] = (__bf16)f3.z; h1[7] = (__bf16)f3.w;
      bf16x8* q = (bf16x8*)(eaS + (size_t)pos * DE);
      q[0] = h0; q[1] = h1;
    }
  }
}

// ---------------- K5/K7: out = (X @ W) * dinv[row]   (N x 128 @ 128 x 128, fp32) -------------
__global__ __launch_bounds__(256) void k_gemm_scale(const float* __restrict__ X,
                                                    const float* __restrict__ W,
                                                    const float* __restrict__ dinv,
                                                    float* __restrict__ out) {
  __shared__ float sX[128][32];
  __shared__ float sW[32][128];
  int tid = threadIdx.x;
  int tx = tid & 15, ty = tid >> 4;
  int rowBase = blockIdx.x * 128;
  float acc[8][8] = {};
  for (int kc = 0; kc < 128; kc += 32) {
    #pragma unroll
    for (int i = 0; i < 4; ++i) {
      int idx = tid + i * 256;          // 0..1023 -> 128 rows x 8 float4
      int r = idx >> 3, kq = idx & 7;
      int row = rowBase + r;
      float4 v = make_float4(0.f, 0.f, 0.f, 0.f);
      if (row < N_NODES) v = *(const float4*)(X + (size_t)row * 128 + kc + kq * 4);
      *(float4*)(&sX[r][kq * 4]) = v;
    }
    #pragma unroll
    for (int i = 0; i < 4; ++i) {
      int idx = tid + i * 256;          // 32 rows x 32 float4
      int k = idx >> 5, cq = idx & 31;
      *(float4*)(&sW[k][cq * 4]) = *(const float4*)(W + (size_t)(kc + k) * 128 + cq * 4);
    }
    __syncthreads();
    #pragma unroll 4
    for (int k = 0; k < 32; ++k) {
      float a[8], b[8];
      #pragma unroll
      for (int j = 0; j < 8; ++j) a[j] = sX[ty * 8 + j][k];
      *(float4*)(&b[0]) = *(float4*)(&sW[k][tx * 8]);
      *(float4*)(&b[4]) = *(float4*)(&sW[k][tx * 8 + 4]);
      #pragma unroll
      for (int j = 0; j < 8; ++j)
        #pragma unroll
        for (int c = 0; c < 8; ++c) acc[j][c] += a[j] * b[c];
    }
    __syncthreads();
  }
  #pragma unroll
  for (int j = 0; j < 8; ++j) {
    int row = rowBase + ty * 8 + j;
    if (row < N_NODES) {
      float dv = dinv[row];
      float4 o0, o1;
      o0.x = acc[j][0] * dv; o0.y = acc[j][1] * dv; o0.z = acc[j][2] * dv; o0.w = acc[j][3] * dv;
      o1.x = acc[j][4] * dv; o1.y = acc[j][5] * dv; o1.z = acc[j][6] * dv; o1.w = acc[j][7] * dv;
      *(float4*)(out + (size_t)row * 128 + tx * 8) = o0;
      *(float4*)(out + (size_t)row * 128 + tx * 8 + 4) = o1;
    }
  }
}

// ---------------- K6: CSR aggregate + bias + BN + ReLU -> out ----------------
__global__ void k_agg_bn(const float* __restrict__ A, const int* __restrict__ nbr,
                         const int* __restrict__ rs, const int* __restrict__ deg,
                         const float* __restrict__ dinv,
                         const float* __restrict__ b, const float* __restrict__ gm,
                         const float* __restrict__ bt, const float* __restrict__ m,
                         const float* __restrict__ v, float* __restrict__ out) {
  int tid = threadIdx.x;
  int c = tid & 127;
  int half = tid >> 7;
  int gid = blockIdx.x * 2 + half;  // 32 nodes per group
  if (gid * 32 >= N_NODES) return;
  float scale = gm[c] * rsqrtf(v[c] + EPSBN);
  float shift = bt[c] - m[c] * scale;
  float bias = b[c];
  int base = gid * 32;
  for (int nn = 0; nn < 32; ++nn) {
    int i = base + nn;
    float sum = A[(size_t)i * 128 + c];   // self loop (already dinv-scaled)
    int j = rs[i];
    int end = j + deg[i] - 1;             // indeg real edges
    for (; j + 3 < end; j += 4) {
      int s0 = nbr[j], s1 = nbr[j + 1], s2 = nbr[j + 2], s3 = nbr[j + 3];
      sum += A[(size_t)s0 * 128 + c];
      sum += A[(size_t)s1 * 128 + c];
      sum += A[(size_t)s2 * 128 + c];
      sum += A[(size_t)s3 * 128 + c];
    }
    for (; j < end; ++j) sum += A[(size_t)nbr[j] * 128 + c];
    float y = dinv[i] * sum + bias;
    out[(size_t)i * 128 + c] = fmaxf(y * scale + shift, 0.f);
  }
}

// ---------------- K8: CSR aggregate + BN + ReLU + sorted-batch mean-pool accumulate ----------
__global__ void k_agg_bn_pool(const float* __restrict__ A, const int* __restrict__ nbr,
                              const int* __restrict__ rs, const int* __restrict__ deg,
                              const float* __restrict__ dinv, const int* __restrict__ batch,
                              const float* __restrict__ b, const float* __restrict__ gm,
                              const float* __restrict__ bt, const float* __restrict__ m,
                              const float* __restrict__ v,
                              float* __restrict__ gsum, float* __restrict__ gcnt) {
  int tid = threadIdx.x;
  int c = tid & 127;
  int half = tid >> 7;
  int gid = blockIdx.x * 2 + half;
  if (gid * 32 >= N_NODES) return;
  float scale = gm[c] * rsqrtf(v[c] + EPSBN);
  float shift = bt[c] - m[c] * scale;
  float bias = b[c];
  int base = gid * 32;
  float acc = 0.f, cnt = 0.f;
  int curg = -1;
  for (int nn = 0; nn < 32; ++nn) {
    int i = base + nn;
    int bg = batch[i];
    if (bg != curg) {
      if (curg >= 0) {
        atomicAdd(&gsum[(size_t)curg * 128 + c], acc);
        if (c == 0) atomicAdd(&gcnt[curg], cnt);
      }
      acc = 0.f; cnt = 0.f; curg = bg;
    }
    float sum = A[(size_t)i * 128 + c];
    int j = rs[i];
    int end = j + deg[i] - 1;
    for (; j + 3 < end; j += 4) {
      int s0 = nbr[j], s1 = nbr[j + 1], s2 = nbr[j + 2], s3 = nbr[j + 3];
      sum += A[(size_t)s0 * 128 + c];
      sum += A[(size_t)s1 * 128 + c];
      sum += A[(size_t)s2 * 128 + c];
      sum += A[(size_t)s3 * 128 + c];
    }
    for (; j < end; ++j) sum += A[(size_t)nbr[j] * 128 + c];
    float y = dinv[i] * sum + bias;
    acc += fmaxf(y * scale + shift, 0.f);
    cnt += 1.f;
  }
  atomicAdd(&gsum[(size_t)curg * 128 + c], acc);
  if (c == 0) atomicAdd(&gcnt[curg], cnt);
}

// ---------------- K9: per-graph sum of relu(eaS @ We1 + be1) via bf16 MFMA -------------------
// eaS is graph-sorted bf16 edge features: fully coalesced affine streaming, no indirection.
__global__ __launch_bounds__(256) void k_edge_hidden(
    const __bf16* __restrict__ eaS,
    const int* __restrict__ ebs, const int* __restrict__ ecnt,
    const float* __restrict__ We1, const float* __restrict__ be1,
    float* __restrict__ esum) {
  int tid = threadIdx.x;
  int wave = tid >> 6;
  int lane = tid & 63;
  int n = lane & 15;           // channel-within-block / edge-row index
  int kg = lane >> 4;          // k-group 0..3 (k = kg*8 + j); kg>=2 -> zero pad
  int g = blockIdx.x / ESLICE;
  int slice = blockIdx.x % ESLICE;

  bf16x8 bfrag[8];
  float biasv[8];
  #pragma unroll
  for (int blk = 0; blk < 8; ++blk) {
    #pragma unroll
    for (int j = 0; j < 8; ++j) {
      int k = kg * 8 + j;
      float w = (k < DE) ? We1[k * 128 + blk * 16 + n] : 0.f;
      bfrag[blk][j] = (__bf16)w;
    }
    biasv[blk] = be1[blk * 16 + n];
  }

  int start = ebs[g], cnt = ecnt[g];
  int lim = start + cnt;
  int ntiles = (cnt + 15) >> 4;
  const int nstream = ESLICE * 4;
  int sid = slice * 4 + wave;
  int tpc = (ntiles + nstream - 1) / nstream;
  int t0 = sid * tpc;
  int t1 = t0 + tpc; if (t1 > ntiles) t1 = ntiles;

  float racc[8] = {0.f, 0.f, 0.f, 0.f, 0.f, 0.f, 0.f, 0.f};

  for (int t = t0; t < t1; ++t) {
    int jb = start + (t << 4);
    int row = jb + n;
    int rc = row < lim - 1 ? row : lim - 1;  // clamp tail rows (masked in epilogue)
    bf16x8 afrag = {};
    if (kg < 2) afrag = *(const bf16x8*)(eaS + (size_t)rc * DE + kg * 8);
    bool full = (jb + 16 <= lim);   // wave-uniform
    if (full) {
      #pragma unroll
      for (int blk = 0; blk < 8; ++blk) {
        f32x4 acc = {0.f, 0.f, 0.f, 0.f};
        acc = __builtin_amdgcn_mfma_f32_16x16x32_bf16(afrag, bfrag[blk], acc, 0, 0, 0);
        #pragma unroll
        for (int r = 0; r < 4; ++r)
          racc[blk] += fmaxf(acc[r] + biasv[blk], 0.f);
      }
    } else {
      #pragma unroll
      for (int blk = 0; blk < 8; ++blk) {
        f32x4 acc = {0.f, 0.f, 0.f, 0.f};
        acc = __builtin_amdgcn_mfma_f32_16x16x32_bf16(afrag, bfrag[blk], acc, 0, 0, 0);
        #pragma unroll
        for (int r = 0; r < 4; ++r) {
          int rr = kg * 4 + r;
          if (jb + rr < lim) racc[blk] += fmaxf(acc[r] + biasv[blk], 0.f);
        }
      }
    }
  }

  #pragma unroll
  for (int blk = 0; blk < 8; ++blk) {
    float vsum = racc[blk];
    vsum += __shfl_xor(vsum, 16);
    vsum += __shfl_xor(vsum, 32);
    if (lane < 16) atomicAdd(&esum[(size_t)g * 128 + blk * 16 + n], vsum);
  }
}

// ---------------- K10: graph mean + (edge mean hidden) @ We2 + be2 -> out ----------------
__global__ void k_final(const float* __restrict__ esum, const int* __restrict__ ecnt,
                        const float* __restrict__ gsum, const float* __restrict__ gcnt,
                        const float* __restrict__ We2, const float* __restrict__ be2,
                        float* __restrict__ out) {
  __shared__ float mh[128];
  int g = blockIdx.x, c = threadIdx.x;
  int ec = ecnt[g];
  mh[c] = (ec > 0) ? esum[(size_t)g * 128 + c] / (float)ec : 0.f;
  __syncthreads();
  float acc = 0.f;
  #pragma unroll 8
  for (int k = 0; k < 128; ++k) acc += mh[k] * We2[k * 128 + c];
  float er = (ec > 0) ? (acc + be2[c]) : 0.f;
  float gr = gsum[(size_t)g * 128 + c] / fmaxf(gcnt[g], 1.f);
  out[(size_t)g * 128 + c] = gr + er;
}

extern "C" void kernel_launch(void* const* d_in, const int* in_sizes, int n_in,
                              void* d_out, int out_size, void* d_ws, size_t ws_size,
                              hipStream_t stream) {
  const float* x        = (const float*)d_in[0];
  const int*   ei       = (const int*)d_in[1];     // [2, E]
  const int*   batch    = (const int*)d_in[2];     // [N], sorted
  const float* edge_attr= (const float*)d_in[3];   // [E, 16]
  const float* W1 = (const float*)d_in[5];
  const float* b1 = (const float*)d_in[6];
  const float* g1 = (const float*)d_in[7];
  const float* bt1= (const float*)d_in[8];
  const float* m1 = (const float*)d_in[9];
  const float* v1 = (const float*)d_in[10];
  const float* W2 = (const float*)d_in[11];
  const float* b2 = (const float*)d_in[12];
  const float* g2 = (const float*)d_in[13];
  const float* bt2= (const float*)d_in[14];
  const float* m2 = (const float*)d_in[15];
  const float* v2 = (const float*)d_in[16];
  const float* We1= (const float*)d_in[17];
  const float* be1= (const float*)d_in[18];
  const float* We2= (const float*)d_in[19];
  const float* be2= (const float*)d_in[20];
  float* out = (float*)d_out;

  char* ws = (char*)d_ws;
  size_t off = 0;
  auto take = [&](size_t bytes) -> char* {
    char* p = ws + off;
    off += (bytes + 255) & ~(size_t)255;
    return p;
  };
  float*  A       = (float*)take((size_t)N_NODES * 128 * 4);
  float*  B       = (float*)take((size_t)N_NODES * 128 * 4);
  float*  dinv    = (float*)take((size_t)N_NODES * 4);
  int*    deg     = (int*)  take((size_t)N_NODES * 4);
  int*    rs      = (int*)  take((size_t)N_NODES * 4);
  int*    cursor  = (int*)  take((size_t)N_NODES * 4);
  int*    nbr     = (int*)  take((size_t)(N_EDGES + N_NODES) * 4);
  __bf16* eaS     = (__bf16*)take((size_t)N_EDGES * DE * 2);  // graph-sorted bf16 edge feats
  int*    ecnt    = (int*)  take((size_t)G * 4);
  int*    ebs     = (int*)  take((size_t)G * 4);
  int*    ecur_pad= (int*)  take((size_t)G * 16 * 4);  // 64B-stride cursors
  float*  gcnt    = (float*)take((size_t)G * 4);
  float*  esum    = (float*)take((size_t)G * 128 * 4);
  float*  gsum    = (float*)take((size_t)G * 128 * 4);
  int*    part    = (int*)  take((size_t)NSB * 4);

  k_init<<<(N_NODES + 255) / 256, 256, 0, stream>>>(deg, ecnt, gcnt, gsum, esum);
  k_count<<<(N_EDGES + 4095) / 4096, 256, 0, stream>>>(ei, batch, deg, ecnt);
  // hierarchical scan (+ dinv folded into the write phase)
  k_scan_part<<<NSB, 256, 0, stream>>>(deg, part);
  k_scan_mid<<<1, 512, 0, stream>>>(part, ecnt, ebs, ecur_pad);
  k_scan_write<<<NSB, 256, 0, stream>>>(deg, part, rs, cursor, dinv);
  k_scatter<<<(N_EDGES + EPB - 1) / EPB, 256, 0, stream>>>(ei, batch, edge_attr, cursor, ecur_pad, nbr, eaS);
  // layer 1
  k_gemm_scale<<<(N_NODES + 127) / 128, 256, 0, stream>>>(x, W1, dinv, A);
  k_agg_bn<<<(N_NODES / 32 + 1) / 2 + 1, 256, 0, stream>>>(A, nbr, rs, deg, dinv, b1, g1, bt1, m1, v1, B);
  // layer 2 (+ pooling fused)
  k_gemm_scale<<<(N_NODES + 127) / 128, 256, 0, stream>>>(B, W2, dinv, A);
  k_agg_bn_pool<<<(N_NODES / 32 + 1) / 2 + 1, 256, 0, stream>>>(A, nbr, rs, deg, dinv, batch, b2, g2, bt2, m2, v2, gsum, gcnt);
  // edge path
  k_edge_hidden<<<G * ESLICE, 256, 0, stream>>>(eaS, ebs, ecnt, We1, be1, esum);
  k_final<<<G, 128, 0, stream>>>(esum, ecnt, gsum, gcnt, We2, be2, out);
}

// Round 7
// 799.777 us; speedup vs baseline: 3.4150x; 1.2546x over previous
//
#include <hip/hip_runtime.h>

#define N_NODES 100000
#define N_EDGES 1600000
#define D 128
#define DE 16
#define G 512
#define EPSBN 1e-5f
#define ESLICE 4    // blocks per graph in k_edge_hidden (x4 waves = 16 streams/graph)
#define EPB 1024    // edges per block in k_scatter
#define EPT (EPB / 256)
#define SCHUNK 1024 // nodes per block in hierarchical scan
#define NSB ((N_NODES + SCHUNK - 1) / SCHUNK)  // 98
#define AGG_CH 16   // nodes per wave in agg kernels

typedef __bf16 bf16x8 __attribute__((ext_vector_type(8)));
typedef float f32x4 __attribute__((ext_vector_type(4)));

__device__ __forceinline__ float bf_lo(unsigned v) { return __uint_as_float(v << 16); }
__device__ __forceinline__ float bf_hi(unsigned v) { return __uint_as_float(v & 0xffff0000u); }

// ---------------- K0: init deg=1 (self loop), zero counters/accumulators ----------------
__global__ void k_init(int* __restrict__ deg, int* __restrict__ ecnt,
                       float* __restrict__ gcnt, float* __restrict__ gsum,
                       float* __restrict__ esum) {
  int i = blockIdx.x * 256 + threadIdx.x;
  if (i < N_NODES) deg[i] = 1;
  if (i < G) { ecnt[i] = 0; gcnt[i] = 0.f; }
  if (i < G * D) { gsum[i] = 0.f; esum[i] = 0.f; }
}

// ---------------- K1: count in-degree per node + edges per graph (LDS bins) ----------------
__global__ void k_count(const int* __restrict__ ei, const int* __restrict__ batch,
                        int* __restrict__ deg, int* __restrict__ ecnt) {
  __shared__ int bins[G];
  int tid = threadIdx.x;
  for (int i = tid; i < G; i += 256) bins[i] = 0;
  __syncthreads();
  int base = blockIdx.x * 4096;
  for (int t = tid; t < 4096; t += 256) {
    int e = base + t;
    if (e < N_EDGES) {
      int s = ei[e];
      int d = ei[N_EDGES + e];
      atomicAdd(&deg[d], 1);
      atomicAdd(&bins[batch[s]], 1);
    }
  }
  __syncthreads();
  for (int i = tid; i < G; i += 256) if (bins[i]) atomicAdd(&ecnt[i], bins[i]);
}

// ---------------- K2a: per-block partial sums of deg ----------------
__global__ __launch_bounds__(256) void k_scan_part(const int* __restrict__ deg,
                                                   int* __restrict__ part) {
  __shared__ int red[4];
  int tid = threadIdx.x;
  int base = blockIdx.x * SCHUNK + tid * 4;
  int s = 0;
  #pragma unroll
  for (int k = 0; k < 4; ++k) {
    int i = base + k;
    if (i < N_NODES) s += deg[i];
  }
  #pragma unroll
  for (int off = 32; off > 0; off >>= 1) s += __shfl_down(s, off);
  if ((tid & 63) == 0) red[tid >> 6] = s;
  __syncthreads();
  if (tid == 0) part[blockIdx.x] = red[0] + red[1] + red[2] + red[3];
}

// ---------------- K2b: single block: scan 98 partials + scan 512 ecnt ----------------
__global__ void k_scan_mid(int* __restrict__ part, const int* __restrict__ ecnt,
                           int* __restrict__ ebs, int* __restrict__ ecur_pad) {
  __shared__ int sb[512];
  int tid = threadIdx.x;  // 512 threads
  int v = (tid < NSB) ? part[tid] : 0;
  sb[tid] = v;
  __syncthreads();
  for (int off = 1; off < 512; off <<= 1) {
    int t = (tid >= off) ? sb[tid - off] : 0;
    __syncthreads();
    sb[tid] += t;
    __syncthreads();
  }
  if (tid < NSB) part[tid] = sb[tid] - v;  // exclusive block bases
  __syncthreads();
  int v2 = ecnt[tid];  // G == 512 == blockDim
  sb[tid] = v2;
  __syncthreads();
  for (int off = 1; off < 512; off <<= 1) {
    int t = (tid >= off) ? sb[tid - off] : 0;
    __syncthreads();
    sb[tid] += t;
    __syncthreads();
  }
  ebs[tid] = sb[tid] - v2;
  ecur_pad[tid * 16] = sb[tid] - v2;
}

// ---------------- K2c: write rs/cursor (exclusive prefix) + dinv ----------------
__global__ __launch_bounds__(256) void k_scan_write(const int* __restrict__ deg,
                                                    const int* __restrict__ part,
                                                    int* __restrict__ rs,
                                                    int* __restrict__ cursor,
                                                    float* __restrict__ dinv) {
  __shared__ int sb[256];
  int tid = threadIdx.x;
  int base = blockIdx.x * SCHUNK + tid * 4;
  int d[4];
  int s = 0;
  #pragma unroll
  for (int k = 0; k < 4; ++k) {
    int i = base + k;
    d[k] = (i < N_NODES) ? deg[i] : 0;
    s += d[k];
  }
  sb[tid] = s;
  __syncthreads();
  for (int off = 1; off < 256; off <<= 1) {
    int t = (tid >= off) ? sb[tid - off] : 0;
    __syncthreads();
    sb[tid] += t;
    __syncthreads();
  }
  int ex = sb[tid] - s + part[blockIdx.x];
  #pragma unroll
  for (int k = 0; k < 4; ++k) {
    int i = base + k;
    if (i < N_NODES) {
      rs[i] = ex;
      cursor[i] = ex;
      dinv[i] = rsqrtf((float)d[k]);
      ex += d[k];
    }
  }
}

// ---------------- K4: scatter edges into node-CSR (atomic cursors) and bf16 edge features
// into graph-sorted order (block-local counting sort + direct 32B feature copy) --------------
__global__ __launch_bounds__(256) void k_scatter(const int* __restrict__ ei,
                                                 const int* __restrict__ batch,
                                                 const float* __restrict__ edge_attr,
                                                 int* __restrict__ cursor,
                                                 int* __restrict__ ecur_pad,
                                                 int* __restrict__ nbr,
                                                 __bf16* __restrict__ eaS) {
  __shared__ int bins[G];
  __shared__ int base[G];
  int tid = threadIdx.x;
  for (int i = tid; i < G; i += 256) bins[i] = 0;
  __syncthreads();
  int e0 = blockIdx.x * EPB;
  int ge[EPT], gr[EPT];
  #pragma unroll
  for (int k = 0; k < EPT; ++k) {
    int e = e0 + k * 256 + tid;
    ge[k] = -1;
    if (e < N_EDGES) {
      int s = ei[e], d = ei[N_EDGES + e];
      int pos = atomicAdd(&cursor[d], 1);
      nbr[pos] = s;
      int g = batch[s];
      ge[k] = g;
      gr[k] = atomicAdd(&bins[g], 1);
    }
  }
  __syncthreads();
  for (int i = tid; i < G; i += 256) {
    int cnt = bins[i];
    base[i] = cnt ? atomicAdd(&ecur_pad[i * 16], cnt) : 0;
  }
  __syncthreads();
  #pragma unroll
  for (int k = 0; k < EPT; ++k) {
    if (ge[k] >= 0) {
      int e = e0 + k * 256 + tid;
      int pos = base[ge[k]] + gr[k];
      const float4* p = (const float4*)(edge_attr + (size_t)e * DE);
      float4 f0 = p[0], f1 = p[1], f2 = p[2], f3 = p[3];
      bf16x8 h0, h1;
      h0[0] = (__bf16)f0.x; h0[1] = (__bf16)f0.y; h0[2] = (__bf16)f0.z; h0[3] = (__bf16)f0.w;
      h0[4] = (__bf16)f1.x; h0[5] = (__bf16)f1.y; h0[6] = (__bf16)f1.z; h0[7] = (__bf16)f1.w;
      h1[0] = (__bf16)f2.x; h1[1] = (__bf16)f2.y; h1[2] = (__bf16)f2.z; h1[3] = (__bf16)f2.w;
      h1[4] = (__bf16)f3.x; h1[5] = (__bf16)f3.y; h1[6] = (__bf16)f3.z; h1[7] = (__bf16)f3.w;
      bf16x8* q = (bf16x8*)(eaS + (size_t)pos * DE);
      q[0] = h0; q[1] = h1;
    }
  }
}

// ---------------- K5/K7: out(bf16) = (X @ W) * dinv[row]   (N x 128 @ 128 x 128) ------------
__global__ __launch_bounds__(256) void k_gemm_scale(const float* __restrict__ X,
                                                    const float* __restrict__ W,
                                                    const float* __restrict__ dinv,
                                                    __bf16* __restrict__ out) {
  __shared__ float sX[128][32];
  __shared__ float sW[32][128];
  int tid = threadIdx.x;
  int tx = tid & 15, ty = tid >> 4;
  int rowBase = blockIdx.x * 128;
  float acc[8][8] = {};
  for (int kc = 0; kc < 128; kc += 32) {
    #pragma unroll
    for (int i = 0; i < 4; ++i) {
      int idx = tid + i * 256;          // 0..1023 -> 128 rows x 8 float4
      int r = idx >> 3, kq = idx & 7;
      int row = rowBase + r;
      float4 v = make_float4(0.f, 0.f, 0.f, 0.f);
      if (row < N_NODES) v = *(const float4*)(X + (size_t)row * 128 + kc + kq * 4);
      *(float4*)(&sX[r][kq * 4]) = v;
    }
    #pragma unroll
    for (int i = 0; i < 4; ++i) {
      int idx = tid + i * 256;          // 32 rows x 32 float4
      int k = idx >> 5, cq = idx & 31;
      *(float4*)(&sW[k][cq * 4]) = *(const float4*)(W + (size_t)(kc + k) * 128 + cq * 4);
    }
    __syncthreads();
    #pragma unroll 4
    for (int k = 0; k < 32; ++k) {
      float a[8], b[8];
      #pragma unroll
      for (int j = 0; j < 8; ++j) a[j] = sX[ty * 8 + j][k];
      *(float4*)(&b[0]) = *(float4*)(&sW[k][tx * 8]);
      *(float4*)(&b[4]) = *(float4*)(&sW[k][tx * 8 + 4]);
      #pragma unroll
      for (int j = 0; j < 8; ++j)
        #pragma unroll
        for (int c = 0; c < 8; ++c) acc[j][c] += a[j] * b[c];
    }
    __syncthreads();
  }
  #pragma unroll
  for (int j = 0; j < 8; ++j) {
    int row = rowBase + ty * 8 + j;
    if (row < N_NODES) {
      float dv = dinv[row];
      bf16x8 o;
      #pragma unroll
      for (int c = 0; c < 8; ++c) o[c] = (__bf16)(acc[j][c] * dv);
      *(bf16x8*)(out + (size_t)row * 128 + tx * 8) = o;
    }
  }
}

// ---------------- K6: CSR aggregate (bf16 rows) + bias + BN + ReLU -> fp32 out ---------------
// One wave per 16-node chunk; lane covers channels (2*lane, 2*lane+1) via 4B bf16x2 loads.
__global__ __launch_bounds__(256) void k_agg_bn(const unsigned* __restrict__ Au,
                                                const int* __restrict__ nbr,
                                                const int* __restrict__ rs,
                                                const int* __restrict__ deg,
                                                const float* __restrict__ dinv,
                                                const float* __restrict__ b,
                                                const float* __restrict__ gm,
                                                const float* __restrict__ bt,
                                                const float* __restrict__ m,
                                                const float* __restrict__ v,
                                                float* __restrict__ outB) {
  int tid = threadIdx.x;
  int wave = tid >> 6, lane = tid & 63;
  int c0 = lane * 2, c1 = c0 + 1;
  float sc0 = gm[c0] * rsqrtf(v[c0] + EPSBN), sc1 = gm[c1] * rsqrtf(v[c1] + EPSBN);
  float sh0 = bt[c0] - m[c0] * sc0, sh1 = bt[c1] - m[c1] * sc1;
  float bb0 = b[c0], bb1 = b[c1];
  int base = (blockIdx.x * 4 + wave) * AGG_CH;
  for (int nn = 0; nn < AGG_CH; ++nn) {
    int i = base + nn;
    if (i >= N_NODES) return;
    unsigned sv = Au[(size_t)i * 64 + lane];
    float s0 = bf_lo(sv), s1 = bf_hi(sv);
    int j = rs[i];
    int end = j + deg[i] - 1;
    for (; j + 3 < end; j += 4) {
      int n0 = nbr[j], n1 = nbr[j + 1], n2 = nbr[j + 2], n3 = nbr[j + 3];
      unsigned a0 = Au[(size_t)n0 * 64 + lane];
      unsigned a1 = Au[(size_t)n1 * 64 + lane];
      unsigned a2 = Au[(size_t)n2 * 64 + lane];
      unsigned a3 = Au[(size_t)n3 * 64 + lane];
      s0 += bf_lo(a0) + bf_lo(a1) + bf_lo(a2) + bf_lo(a3);
      s1 += bf_hi(a0) + bf_hi(a1) + bf_hi(a2) + bf_hi(a3);
    }
    for (; j < end; ++j) {
      unsigned a = Au[(size_t)nbr[j] * 64 + lane];
      s0 += bf_lo(a); s1 += bf_hi(a);
    }
    float dv = dinv[i];
    float y0 = fmaxf((dv * s0 + bb0) * sc0 + sh0, 0.f);
    float y1 = fmaxf((dv * s1 + bb1) * sc1 + sh1, 0.f);
    *(float2*)(outB + (size_t)i * 128 + c0) = make_float2(y0, y1);
  }
}

// ---------------- K8: CSR aggregate (bf16) + BN + ReLU + sorted-batch mean-pool --------------
__global__ __launch_bounds__(256) void k_agg_bn_pool(const unsigned* __restrict__ Au,
                                                     const int* __restrict__ nbr,
                                                     const int* __restrict__ rs,
                                                     const int* __restrict__ deg,
                                                     const float* __restrict__ dinv,
                                                     const int* __restrict__ batch,
                                                     const float* __restrict__ b,
                                                     const float* __restrict__ gm,
                                                     const float* __restrict__ bt,
                                                     const float* __restrict__ m,
                                                     const float* __restrict__ v,
                                                     float* __restrict__ gsum,
                                                     float* __restrict__ gcnt) {
  int tid = threadIdx.x;
  int wave = tid >> 6, lane = tid & 63;
  int c0 = lane * 2, c1 = c0 + 1;
  float sc0 = gm[c0] * rsqrtf(v[c0] + EPSBN), sc1 = gm[c1] * rsqrtf(v[c1] + EPSBN);
  float sh0 = bt[c0] - m[c0] * sc0, sh1 = bt[c1] - m[c1] * sc1;
  float bb0 = b[c0], bb1 = b[c1];
  int base = (blockIdx.x * 4 + wave) * AGG_CH;
  if (base >= N_NODES) return;
  float acc0 = 0.f, acc1 = 0.f, cnt = 0.f;
  int curg = -1;
  for (int nn = 0; nn < AGG_CH; ++nn) {
    int i = base + nn;
    if (i >= N_NODES) break;
    int bg = batch[i];
    if (bg != curg) {
      if (curg >= 0) {
        atomicAdd(&gsum[(size_t)curg * 128 + c0], acc0);
        atomicAdd(&gsum[(size_t)curg * 128 + c1], acc1);
        if (lane == 0) atomicAdd(&gcnt[curg], cnt);
      }
      acc0 = 0.f; acc1 = 0.f; cnt = 0.f; curg = bg;
    }
    unsigned sv = Au[(size_t)i * 64 + lane];
    float s0 = bf_lo(sv), s1 = bf_hi(sv);
    int j = rs[i];
    int end = j + deg[i] - 1;
    for (; j + 3 < end; j += 4) {
      int n0 = nbr[j], n1 = nbr[j + 1], n2 = nbr[j + 2], n3 = nbr[j + 3];
      unsigned a0 = Au[(size_t)n0 * 64 + lane];
      unsigned a1 = Au[(size_t)n1 * 64 + lane];
      unsigned a2 = Au[(size_t)n2 * 64 + lane];
      unsigned a3 = Au[(size_t)n3 * 64 + lane];
      s0 += bf_lo(a0) + bf_lo(a1) + bf_lo(a2) + bf_lo(a3);
      s1 += bf_hi(a0) + bf_hi(a1) + bf_hi(a2) + bf_hi(a3);
    }
    for (; j < end; ++j) {
      unsigned a = Au[(size_t)nbr[j] * 64 + lane];
      s0 += bf_lo(a); s1 += bf_hi(a);
    }
    float dv = dinv[i];
    acc0 += fmaxf((dv * s0 + bb0) * sc0 + sh0, 0.f);
    acc1 += fmaxf((dv * s1 + bb1) * sc1 + sh1, 0.f);
    cnt += 1.f;
  }
  if (curg >= 0) {
    atomicAdd(&gsum[(size_t)curg * 128 + c0], acc0);
    atomicAdd(&gsum[(size_t)curg * 128 + c1], acc1);
    if (lane == 0) atomicAdd(&gcnt[curg], cnt);
  }
}

// ---------------- K9: per-graph sum of relu(eaS @ We1 + be1) via bf16 MFMA -------------------
__global__ __launch_bounds__(256) void k_edge_hidden(
    const __bf16* __restrict__ eaS,
    const int* __restrict__ ebs, const int* __restrict__ ecnt,
    const float* __restrict__ We1, const float* __restrict__ be1,
    float* __restrict__ esum) {
  int tid = threadIdx.x;
  int wave = tid >> 6;
  int lane = tid & 63;
  int n = lane & 15;           // channel-within-block / edge-row index
  int kg = lane >> 4;          // k-group 0..3 (k = kg*8 + j); kg>=2 -> zero pad
  int g = blockIdx.x / ESLICE;
  int slice = blockIdx.x % ESLICE;

  bf16x8 bfrag[8];
  float biasv[8];
  #pragma unroll
  for (int blk = 0; blk < 8; ++blk) {
    #pragma unroll
    for (int j = 0; j < 8; ++j) {
      int k = kg * 8 + j;
      float w = (k < DE) ? We1[k * 128 + blk * 16 + n] : 0.f;
      bfrag[blk][j] = (__bf16)w;
    }
    biasv[blk] = be1[blk * 16 + n];
  }

  int start = ebs[g], cnt = ecnt[g];
  int lim = start + cnt;
  int ntiles = (cnt + 15) >> 4;
  const int nstream = ESLICE * 4;
  int sid = slice * 4 + wave;
  int tpc = (ntiles + nstream - 1) / nstream;
  int t0 = sid * tpc;
  int t1 = t0 + tpc; if (t1 > ntiles) t1 = ntiles;

  float racc[8] = {0.f, 0.f, 0.f, 0.f, 0.f, 0.f, 0.f, 0.f};

  for (int t = t0; t < t1; ++t) {
    int jb = start + (t << 4);
    int row = jb + n;
    int rc = row < lim - 1 ? row : lim - 1;  // clamp tail rows (masked in epilogue)
    bf16x8 afrag = {};
    if (kg < 2) afrag = *(const bf16x8*)(eaS + (size_t)rc * DE + kg * 8);
    bool full = (jb + 16 <= lim);   // wave-uniform
    if (full) {
      #pragma unroll
      for (int blk = 0; blk < 8; ++blk) {
        f32x4 acc = {0.f, 0.f, 0.f, 0.f};
        acc = __builtin_amdgcn_mfma_f32_16x16x32_bf16(afrag, bfrag[blk], acc, 0, 0, 0);
        #pragma unroll
        for (int r = 0; r < 4; ++r)
          racc[blk] += fmaxf(acc[r] + biasv[blk], 0.f);
      }
    } else {
      #pragma unroll
      for (int blk = 0; blk < 8; ++blk) {
        f32x4 acc = {0.f, 0.f, 0.f, 0.f};
        acc = __builtin_amdgcn_mfma_f32_16x16x32_bf16(afrag, bfrag[blk], acc, 0, 0, 0);
        #pragma unroll
        for (int r = 0; r < 4; ++r) {
          int rr = kg * 4 + r;
          if (jb + rr < lim) racc[blk] += fmaxf(acc[r] + biasv[blk], 0.f);
        }
      }
    }
  }

  #pragma unroll
  for (int blk = 0; blk < 8; ++blk) {
    float vsum = racc[blk];
    vsum += __shfl_xor(vsum, 16);
    vsum += __shfl_xor(vsum, 32);
    if (lane < 16) atomicAdd(&esum[(size_t)g * 128 + blk * 16 + n], vsum);
  }
}

// ---------------- K10: graph mean + (edge mean hidden) @ We2 + be2 -> out ----------------
__global__ void k_final(const float* __restrict__ esum, const int* __restrict__ ecnt,
                        const float* __restrict__ gsum, const float* __restrict__ gcnt,
                        const float* __restrict__ We2, const float* __restrict__ be2,
                        float* __restrict__ out) {
  __shared__ float mh[128];
  int g = blockIdx.x, c = threadIdx.x;
  int ec = ecnt[g];
  mh[c] = (ec > 0) ? esum[(size_t)g * 128 + c] / (float)ec : 0.f;
  __syncthreads();
  float acc = 0.f;
  #pragma unroll 8
  for (int k = 0; k < 128; ++k) acc += mh[k] * We2[k * 128 + c];
  float er = (ec > 0) ? (acc + be2[c]) : 0.f;
  float gr = gsum[(size_t)g * 128 + c] / fmaxf(gcnt[g], 1.f);
  out[(size_t)g * 128 + c] = gr + er;
}

extern "C" void kernel_launch(void* const* d_in, const int* in_sizes, int n_in,
                              void* d_out, int out_size, void* d_ws, size_t ws_size,
                              hipStream_t stream) {
  const float* x        = (const float*)d_in[0];
  const int*   ei       = (const int*)d_in[1];     // [2, E]
  const int*   batch    = (const int*)d_in[2];     // [N], sorted
  const float* edge_attr= (const float*)d_in[3];   // [E, 16]
  const float* W1 = (const float*)d_in[5];
  const float* b1 = (const float*)d_in[6];
  const float* g1 = (const float*)d_in[7];
  const float* bt1= (const float*)d_in[8];
  const float* m1 = (const float*)d_in[9];
  const float* v1 = (const float*)d_in[10];
  const float* W2 = (const float*)d_in[11];
  const float* b2 = (const float*)d_in[12];
  const float* g2 = (const float*)d_in[13];
  const float* bt2= (const float*)d_in[14];
  const float* m2 = (const float*)d_in[15];
  const float* v2 = (const float*)d_in[16];
  const float* We1= (const float*)d_in[17];
  const float* be1= (const float*)d_in[18];
  const float* We2= (const float*)d_in[19];
  const float* be2= (const float*)d_in[20];
  float* out = (float*)d_out;

  char* ws = (char*)d_ws;
  size_t off = 0;
  auto take = [&](size_t bytes) -> char* {
    char* p = ws + off;
    off += (bytes + 255) & ~(size_t)255;
    return p;
  };
  __bf16* A       = (__bf16*)take((size_t)N_NODES * 128 * 2);  // gemm out (bf16, gathered by agg)
  float*  B       = (float*) take((size_t)N_NODES * 128 * 4);  // layer-1 hidden (fp32, gemm2 input)
  float*  dinv    = (float*) take((size_t)N_NODES * 4);
  int*    deg     = (int*)   take((size_t)N_NODES * 4);
  int*    rs      = (int*)   take((size_t)N_NODES * 4);
  int*    cursor  = (int*)   take((size_t)N_NODES * 4);
  int*    nbr     = (int*)   take((size_t)(N_EDGES + N_NODES) * 4);
  __bf16* eaS     = (__bf16*)take((size_t)N_EDGES * DE * 2);   // graph-sorted bf16 edge feats
  int*    ecnt    = (int*)   take((size_t)G * 4);
  int*    ebs     = (int*)   take((size_t)G * 4);
  int*    ecur_pad= (int*)   take((size_t)G * 16 * 4);  // 64B-stride cursors
  float*  gcnt    = (float*) take((size_t)G * 4);
  float*  esum    = (float*) take((size_t)G * 128 * 4);
  float*  gsum    = (float*) take((size_t)G * 128 * 4);
  int*    part    = (int*)   take((size_t)NSB * 4);

  k_init<<<(N_NODES + 255) / 256, 256, 0, stream>>>(deg, ecnt, gcnt, gsum, esum);
  k_count<<<(N_EDGES + 4095) / 4096, 256, 0, stream>>>(ei, batch, deg, ecnt);
  // hierarchical scan (+ dinv folded into the write phase)
  k_scan_part<<<NSB, 256, 0, stream>>>(deg, part);
  k_scan_mid<<<1, 512, 0, stream>>>(part, ecnt, ebs, ecur_pad);
  k_scan_write<<<NSB, 256, 0, stream>>>(deg, part, rs, cursor, dinv);
  k_scatter<<<(N_EDGES + EPB - 1) / EPB, 256, 0, stream>>>(ei, batch, edge_attr, cursor, ecur_pad, nbr, eaS);
  const int aggBlocks = (N_NODES + 4 * AGG_CH - 1) / (4 * AGG_CH);
  // layer 1
  k_gemm_scale<<<(N_NODES + 127) / 128, 256, 0, stream>>>(x, W1, dinv, A);
  k_agg_bn<<<aggBlocks, 256, 0, stream>>>((const unsigned*)A, nbr, rs, deg, dinv, b1, g1, bt1, m1, v1, B);
  // layer 2 (+ pooling fused)
  k_gemm_scale<<<(N_NODES + 127) / 128, 256, 0, stream>>>(B, W2, dinv, A);
  k_agg_bn_pool<<<aggBlocks, 256, 0, stream>>>((const unsigned*)A, nbr, rs, deg, dinv, batch, b2, g2, bt2, m2, v2, gsum, gcnt);
  // edge path
  k_edge_hidden<<<G * ESLICE, 256, 0, stream>>>(eaS, ebs, ecnt, We1, be1, esum);
  k_final<<<G, 128, 0, stream>>>(esum, ecnt, gsum, gcnt, We2, be2, out);
}

// Round 8
// 726.754 us; speedup vs baseline: 3.7581x; 1.1005x over previous
//
#include <hip/hip_runtime.h>

#define N_NODES 100000
#define N_EDGES 1600000
#define D 128
#define DE 16
#define G 512
#define EPSBN 1e-5f
#define ESLICE 4    // blocks per graph in k_edge_hidden
#define EPB 1024    // edges per block in k_scatter
#define EPT (EPB / 256)
#define SCHUNK 1024 // nodes per block in hierarchical scan
#define NSB ((N_NODES + SCHUNK - 1) / SCHUNK)  // 98
#define AGG_CH 16   // nodes per wave in agg kernels
#define DSHIFT 9
#define DBSZ 512
#define NBKT ((N_NODES + DBSZ - 1) / DBSZ)     // 196

typedef __bf16 bf16x8 __attribute__((ext_vector_type(8)));
typedef __bf16 bf16x4 __attribute__((ext_vector_type(4)));
typedef float f32x4 __attribute__((ext_vector_type(4)));

__device__ __forceinline__ float bf_lo(unsigned v) { return __uint_as_float(v << 16); }
__device__ __forceinline__ float bf_hi(unsigned v) { return __uint_as_float(v & 0xffff0000u); }

// ---------------- K0: init deg=1 (self loop), zero counters/accumulators ----------------
__global__ void k_init(int* __restrict__ deg, int* __restrict__ ecnt, int* __restrict__ dcnt,
                       float* __restrict__ gcnt, float* __restrict__ gsum,
                       float* __restrict__ esum) {
  int i = blockIdx.x * 256 + threadIdx.x;
  if (i < N_NODES) deg[i] = 1;
  if (i < G) { ecnt[i] = 0; gcnt[i] = 0.f; }
  if (i < NBKT) dcnt[i] = 0;
  if (i < G * D) { gsum[i] = 0.f; esum[i] = 0.f; }
}

// ---------------- K1: count in-degree, edges/graph, edges/dst-bucket (LDS bins) --------------
__global__ void k_count(const int* __restrict__ ei, const int* __restrict__ batch,
                        int* __restrict__ deg, int* __restrict__ ecnt, int* __restrict__ dcnt) {
  __shared__ int bins[G];
  __shared__ int dbins[NBKT];
  int tid = threadIdx.x;
  for (int i = tid; i < G; i += 256) bins[i] = 0;
  for (int i = tid; i < NBKT; i += 256) dbins[i] = 0;
  __syncthreads();
  int base = blockIdx.x * 4096;
  for (int t = tid; t < 4096; t += 256) {
    int e = base + t;
    if (e < N_EDGES) {
      int s = ei[e];
      int d = ei[N_EDGES + e];
      atomicAdd(&deg[d], 1);
      atomicAdd(&bins[batch[s]], 1);
      atomicAdd(&dbins[d >> DSHIFT], 1);
    }
  }
  __syncthreads();
  for (int i = tid; i < G; i += 256) if (bins[i]) atomicAdd(&ecnt[i], bins[i]);
  for (int i = tid; i < NBKT; i += 256) if (dbins[i]) atomicAdd(&dcnt[i], dbins[i]);
}

// ---------------- K2a: per-block partial sums of deg ----------------
__global__ __launch_bounds__(256) void k_scan_part(const int* __restrict__ deg,
                                                   int* __restrict__ part) {
  __shared__ int red[4];
  int tid = threadIdx.x;
  int base = blockIdx.x * SCHUNK + tid * 4;
  int s = 0;
  #pragma unroll
  for (int k = 0; k < 4; ++k) {
    int i = base + k;
    if (i < N_NODES) s += deg[i];
  }
  #pragma unroll
  for (int off = 32; off > 0; off >>= 1) s += __shfl_down(s, off);
  if ((tid & 63) == 0) red[tid >> 6] = s;
  __syncthreads();
  if (tid == 0) part[blockIdx.x] = red[0] + red[1] + red[2] + red[3];
}

// ---------------- K2b: single block: scan partials + ecnt + dcnt ----------------
__global__ void k_scan_mid(int* __restrict__ part, const int* __restrict__ ecnt,
                           int* __restrict__ ebs, int* __restrict__ ecur_pad,
                           const int* __restrict__ dcnt, int* __restrict__ dbs,
                           int* __restrict__ dcur_pad) {
  __shared__ int sb[512];
  int tid = threadIdx.x;  // 512 threads
  int v = (tid < NSB) ? part[tid] : 0;
  sb[tid] = v;
  __syncthreads();
  for (int off = 1; off < 512; off <<= 1) {
    int t = (tid >= off) ? sb[tid - off] : 0;
    __syncthreads();
    sb[tid] += t;
    __syncthreads();
  }
  if (tid < NSB) part[tid] = sb[tid] - v;
  __syncthreads();
  int v2 = ecnt[tid];
  sb[tid] = v2;
  __syncthreads();
  for (int off = 1; off < 512; off <<= 1) {
    int t = (tid >= off) ? sb[tid - off] : 0;
    __syncthreads();
    sb[tid] += t;
    __syncthreads();
  }
  ebs[tid] = sb[tid] - v2;
  ecur_pad[tid * 16] = sb[tid] - v2;
  __syncthreads();
  int v3 = (tid < NBKT) ? dcnt[tid] : 0;
  sb[tid] = v3;
  __syncthreads();
  for (int off = 1; off < 512; off <<= 1) {
    int t = (tid >= off) ? sb[tid - off] : 0;
    __syncthreads();
    sb[tid] += t;
    __syncthreads();
  }
  if (tid < NBKT) { dbs[tid] = sb[tid] - v3; dcur_pad[tid * 16] = sb[tid] - v3; }
}

// ---------------- K2c: write rs (exclusive prefix) + dinv ----------------
__global__ __launch_bounds__(256) void k_scan_write(const int* __restrict__ deg,
                                                    const int* __restrict__ part,
                                                    int* __restrict__ rs,
                                                    float* __restrict__ dinv) {
  __shared__ int sb[256];
  int tid = threadIdx.x;
  int base = blockIdx.x * SCHUNK + tid * 4;
  int d[4];
  int s = 0;
  #pragma unroll
  for (int k = 0; k < 4; ++k) {
    int i = base + k;
    d[k] = (i < N_NODES) ? deg[i] : 0;
    s += d[k];
  }
  sb[tid] = s;
  __syncthreads();
  for (int off = 1; off < 256; off <<= 1) {
    int t = (tid >= off) ? sb[tid - off] : 0;
    __syncthreads();
    sb[tid] += t;
    __syncthreads();
  }
  int ex = sb[tid] - s + part[blockIdx.x];
  #pragma unroll
  for (int k = 0; k < 4; ++k) {
    int i = base + k;
    if (i < N_NODES) {
      rs[i] = ex;
      dinv[i] = rsqrtf((float)d[k]);
      ex += d[k];
    }
  }
}

// ---------------- K4a: counting-sort edges into graph bins (bf16 features) and dst-bucket
// (src,dst) pairs; block-local LDS ranks + one padded global reservation per bin -------------
__global__ __launch_bounds__(256) void k_scatter(const int* __restrict__ ei,
                                                 const int* __restrict__ batch,
                                                 const float* __restrict__ edge_attr,
                                                 int* __restrict__ ecur_pad,
                                                 int* __restrict__ dcur_pad,
                                                 int2* __restrict__ pairs,
                                                 __bf16* __restrict__ eaS) {
  __shared__ int gbins[G];
  __shared__ int gbase[G];
  __shared__ int dbins[NBKT];
  __shared__ int dbase[NBKT];
  int tid = threadIdx.x;
  for (int i = tid; i < G; i += 256) gbins[i] = 0;
  for (int i = tid; i < NBKT; i += 256) dbins[i] = 0;
  __syncthreads();
  int e0 = blockIdx.x * EPB;
  int ge[EPT], gr[EPT], db[EPT], dr[EPT];
  #pragma unroll
  for (int k = 0; k < EPT; ++k) {
    int e = e0 + k * 256 + tid;
    ge[k] = -1;
    if (e < N_EDGES) {
      int s = ei[e], d = ei[N_EDGES + e];
      int g = batch[s];
      ge[k] = g;
      gr[k] = atomicAdd(&gbins[g], 1);
      db[k] = d >> DSHIFT;
      dr[k] = atomicAdd(&dbins[db[k]], 1);
    }
  }
  __syncthreads();
  for (int i = tid; i < G; i += 256) {
    int cnt = gbins[i];
    gbase[i] = cnt ? atomicAdd(&ecur_pad[i * 16], cnt) : 0;
  }
  for (int i = tid; i < NBKT; i += 256) {
    int cnt = dbins[i];
    dbase[i] = cnt ? atomicAdd(&dcur_pad[i * 16], cnt) : 0;
  }
  __syncthreads();
  #pragma unroll
  for (int k = 0; k < EPT; ++k) {
    if (ge[k] >= 0) {
      int e = e0 + k * 256 + tid;
      int s = ei[e], d = ei[N_EDGES + e];
      // graph-sorted bf16 feature copy
      int gpos = gbase[ge[k]] + gr[k];
      const float4* p = (const float4*)(edge_attr + (size_t)e * DE);
      float4 f0 = p[0], f1 = p[1], f2 = p[2], f3 = p[3];
      bf16x8 h0, h1;
      h0[0] = (__bf16)f0.x; h0[1] = (__bf16)f0.y; h0[2] = (__bf16)f0.z; h0[3] = (__bf16)f0.w;
      h0[4] = (__bf16)f1.x; h0[5] = (__bf16)f1.y; h0[6] = (__bf16)f1.z; h0[7] = (__bf16)f1.w;
      h1[0] = (__bf16)f2.x; h1[1] = (__bf16)f2.y; h1[2] = (__bf16)f2.z; h1[3] = (__bf16)f2.w;
      h1[4] = (__bf16)f3.x; h1[5] = (__bf16)f3.y; h1[6] = (__bf16)f3.z; h1[7] = (__bf16)f3.w;
      bf16x8* q = (bf16x8*)(eaS + (size_t)gpos * DE);
      q[0] = h0; q[1] = h1;
      // dst-bucket pair
      pairs[dbase[db[k]] + dr[k]] = make_int2(s, d);
    }
  }
}

// ---------------- K4b: per-bucket CSR fill — block exclusively owns 512 nodes; cursors in LDS,
// nbr writes confined to the bucket's contiguous CSR range (no global atomics, no line thrash)
__global__ __launch_bounds__(256) void k_scatter_nbr(const int2* __restrict__ pairs,
                                                     const int* __restrict__ dbs,
                                                     const int* __restrict__ dcnt,
                                                     const int* __restrict__ rs,
                                                     int* __restrict__ nbr) {
  __shared__ int cur[DBSZ];
  int tid = threadIdx.x;
  int bkt = blockIdx.x;
  int nodeBase = bkt << DSHIFT;
  for (int l = tid; l < DBSZ; l += 256) {
    int node = nodeBase + l;
    cur[l] = (node < N_NODES) ? rs[node] : 0;
  }
  __syncthreads();
  int start = dbs[bkt], n = dcnt[bkt];
  for (int i = tid; i < n; i += 256) {
    int2 p = pairs[start + i];
    int pos = atomicAdd(&cur[p.y - nodeBase], 1);
    nbr[pos] = p.x;
  }
}

// ---------------- K5pre: convert W (128x128 fp32) to MFMA B-fragment layout bf16 -------------
// Wf[((kc*8+cb)*64+lane)*8+j] = W[kc*32+(lane>>4)*8+j][cb*16+(lane&15)]
__global__ void k_prep_w(const float* __restrict__ W, __bf16* __restrict__ Wf) {
  int tid = threadIdx.x;
  for (int idx = blockIdx.x * 256 + tid; idx < 16384; idx += 8 * 256) {
    int j = idx & 7;
    int lane = (idx >> 3) & 63;
    int cb = (idx >> 9) & 7;
    int kc = idx >> 12;
    int k = kc * 32 + (lane >> 4) * 8 + j;
    int n = cb * 16 + (lane & 15);
    Wf[idx] = (__bf16)W[k * 128 + n];
  }
}

// ---------------- K5/K7: out(bf16) = (X @ W) * dinv[row] via bf16 MFMA ----------------------
// 64-row block tile; X staged to LDS bf16 (row pad +8 -> conflict-free b128); W frags global.
__global__ __launch_bounds__(256) void k_gemm_mfma(const float* __restrict__ X,
                                                   const __bf16* __restrict__ Wf,
                                                   const float* __restrict__ dinv,
                                                   __bf16* __restrict__ out) {
  __shared__ __bf16 sXb[64][136];
  int tid = threadIdx.x;
  int wave = tid >> 6, lane = tid & 63;
  int m = lane & 15, kg = lane >> 4;
  int base = blockIdx.x * 64;
  // stage 64 x 128 fp32 -> bf16 LDS
  #pragma unroll
  for (int i = 0; i < 8; ++i) {
    int idx = tid + i * 256;          // 2048 float4 chunks
    int r = idx >> 5, cq = idx & 31;
    int row = base + r;
    float4 v = make_float4(0.f, 0.f, 0.f, 0.f);
    if (row < N_NODES) v = *(const float4*)(X + (size_t)row * 128 + cq * 4);
    bf16x4 h;
    h[0] = (__bf16)v.x; h[1] = (__bf16)v.y; h[2] = (__bf16)v.z; h[3] = (__bf16)v.w;
    *(bf16x4*)(&sXb[r][cq * 4]) = h;
  }
  __syncthreads();
  int r0 = wave * 16;
  f32x4 acc[8];
  #pragma unroll
  for (int cb = 0; cb < 8; ++cb) acc[cb] = (f32x4){0.f, 0.f, 0.f, 0.f};
  #pragma unroll
  for (int kc = 0; kc < 4; ++kc) {
    bf16x8 afrag = *(const bf16x8*)(&sXb[r0 + m][kc * 32 + kg * 8]);
    #pragma unroll
    for (int cb = 0; cb < 8; ++cb) {
      bf16x8 bfrag = *(const bf16x8*)(Wf + (((size_t)(kc * 8 + cb) * 64 + lane) << 3));
      acc[cb] = __builtin_amdgcn_mfma_f32_16x16x32_bf16(afrag, bfrag, acc[cb], 0, 0, 0);
    }
  }
  // epilogue: C row = kg*4+r, col = cb*16+m
  #pragma unroll
  for (int r = 0; r < 4; ++r) {
    int grow = base + r0 + kg * 4 + r;
    if (grow < N_NODES) {
      float dv = dinv[grow];
      #pragma unroll
      for (int cb = 0; cb < 8; ++cb)
        out[(size_t)grow * 128 + cb * 16 + m] = (__bf16)(acc[cb][r] * dv);
    }
  }
}

// ---------------- K6: CSR aggregate (bf16 rows) + bias + BN + ReLU -> fp32 out ---------------
__global__ __launch_bounds__(256) void k_agg_bn(const unsigned* __restrict__ Au,
                                                const int* __restrict__ nbr,
                                                const int* __restrict__ rs,
                                                const int* __restrict__ deg,
                                                const float* __restrict__ dinv,
                                                const float* __restrict__ b,
                                                const float* __restrict__ gm,
                                                const float* __restrict__ bt,
                                                const float* __restrict__ m,
                                                const float* __restrict__ v,
                                                float* __restrict__ outB) {
  int tid = threadIdx.x;
  int wave = tid >> 6, lane = tid & 63;
  int c0 = lane * 2, c1 = c0 + 1;
  float sc0 = gm[c0] * rsqrtf(v[c0] + EPSBN), sc1 = gm[c1] * rsqrtf(v[c1] + EPSBN);
  float sh0 = bt[c0] - m[c0] * sc0, sh1 = bt[c1] - m[c1] * sc1;
  float bb0 = b[c0], bb1 = b[c1];
  int base = (blockIdx.x * 4 + wave) * AGG_CH;
  for (int nn = 0; nn < AGG_CH; ++nn) {
    int i = base + nn;
    if (i >= N_NODES) return;
    unsigned sv = Au[(size_t)i * 64 + lane];
    float s0 = bf_lo(sv), s1 = bf_hi(sv);
    int j = rs[i];
    int end = j + deg[i] - 1;
    for (; j + 3 < end; j += 4) {
      int n0 = nbr[j], n1 = nbr[j + 1], n2 = nbr[j + 2], n3 = nbr[j + 3];
      unsigned a0 = Au[(size_t)n0 * 64 + lane];
      unsigned a1 = Au[(size_t)n1 * 64 + lane];
      unsigned a2 = Au[(size_t)n2 * 64 + lane];
      unsigned a3 = Au[(size_t)n3 * 64 + lane];
      s0 += bf_lo(a0) + bf_lo(a1) + bf_lo(a2) + bf_lo(a3);
      s1 += bf_hi(a0) + bf_hi(a1) + bf_hi(a2) + bf_hi(a3);
    }
    for (; j < end; ++j) {
      unsigned a = Au[(size_t)nbr[j] * 64 + lane];
      s0 += bf_lo(a); s1 += bf_hi(a);
    }
    float dv = dinv[i];
    float y0 = fmaxf((dv * s0 + bb0) * sc0 + sh0, 0.f);
    float y1 = fmaxf((dv * s1 + bb1) * sc1 + sh1, 0.f);
    *(float2*)(outB + (size_t)i * 128 + c0) = make_float2(y0, y1);
  }
}

// ---------------- K8: CSR aggregate (bf16) + BN + ReLU + sorted-batch mean-pool --------------
__global__ __launch_bounds__(256) void k_agg_bn_pool(const unsigned* __restrict__ Au,
                                                     const int* __restrict__ nbr,
                                                     const int* __restrict__ rs,
                                                     const int* __restrict__ deg,
                                                     const float* __restrict__ dinv,
                                                     const int* __restrict__ batch,
                                                     const float* __restrict__ b,
                                                     const float* __restrict__ gm,
                                                     const float* __restrict__ bt,
                                                     const float* __restrict__ m,
                                                     const float* __restrict__ v,
                                                     float* __restrict__ gsum,
                                                     float* __restrict__ gcnt) {
  int tid = threadIdx.x;
  int wave = tid >> 6, lane = tid & 63;
  int c0 = lane * 2, c1 = c0 + 1;
  float sc0 = gm[c0] * rsqrtf(v[c0] + EPSBN), sc1 = gm[c1] * rsqrtf(v[c1] + EPSBN);
  float sh0 = bt[c0] - m[c0] * sc0, sh1 = bt[c1] - m[c1] * sc1;
  float bb0 = b[c0], bb1 = b[c1];
  int base = (blockIdx.x * 4 + wave) * AGG_CH;
  if (base >= N_NODES) return;
  float acc0 = 0.f, acc1 = 0.f, cnt = 0.f;
  int curg = -1;
  for (int nn = 0; nn < AGG_CH; ++nn) {
    int i = base + nn;
    if (i >= N_NODES) break;
    int bg = batch[i];
    if (bg != curg) {
      if (curg >= 0) {
        atomicAdd(&gsum[(size_t)curg * 128 + c0], acc0);
        atomicAdd(&gsum[(size_t)curg * 128 + c1], acc1);
        if (lane == 0) atomicAdd(&gcnt[curg], cnt);
      }
      acc0 = 0.f; acc1 = 0.f; cnt = 0.f; curg = bg;
    }
    unsigned sv = Au[(size_t)i * 64 + lane];
    float s0 = bf_lo(sv), s1 = bf_hi(sv);
    int j = rs[i];
    int end = j + deg[i] - 1;
    for (; j + 3 < end; j += 4) {
      int n0 = nbr[j], n1 = nbr[j + 1], n2 = nbr[j + 2], n3 = nbr[j + 3];
      unsigned a0 = Au[(size_t)n0 * 64 + lane];
      unsigned a1 = Au[(size_t)n1 * 64 + lane];
      unsigned a2 = Au[(size_t)n2 * 64 + lane];
      unsigned a3 = Au[(size_t)n3 * 64 + lane];
      s0 += bf_lo(a0) + bf_lo(a1) + bf_lo(a2) + bf_lo(a3);
      s1 += bf_hi(a0) + bf_hi(a1) + bf_hi(a2) + bf_hi(a3);
    }
    for (; j < end; ++j) {
      unsigned a = Au[(size_t)nbr[j] * 64 + lane];
      s0 += bf_lo(a); s1 += bf_hi(a);
    }
    float dv = dinv[i];
    acc0 += fmaxf((dv * s0 + bb0) * sc0 + sh0, 0.f);
    acc1 += fmaxf((dv * s1 + bb1) * sc1 + sh1, 0.f);
    cnt += 1.f;
  }
  if (curg >= 0) {
    atomicAdd(&gsum[(size_t)curg * 128 + c0], acc0);
    atomicAdd(&gsum[(size_t)curg * 128 + c1], acc1);
    if (lane == 0) atomicAdd(&gcnt[curg], cnt);
  }
}

// ---------------- K9: per-graph sum of relu(eaS @ We1 + be1) via bf16 MFMA -------------------
__global__ __launch_bounds__(256) void k_edge_hidden(
    const __bf16* __restrict__ eaS,
    const int* __restrict__ ebs, const int* __restrict__ ecnt,
    const float* __restrict__ We1, const float* __restrict__ be1,
    float* __restrict__ esum) {
  int tid = threadIdx.x;
  int wave = tid >> 6;
  int lane = tid & 63;
  int n = lane & 15;
  int kg = lane >> 4;
  int g = blockIdx.x / ESLICE;
  int slice = blockIdx.x % ESLICE;

  bf16x8 bfrag[8];
  float biasv[8];
  #pragma unroll
  for (int blk = 0; blk < 8; ++blk) {
    #pragma unroll
    for (int j = 0; j < 8; ++j) {
      int k = kg * 8 + j;
      float w = (k < DE) ? We1[k * 128 + blk * 16 + n] : 0.f;
      bfrag[blk][j] = (__bf16)w;
    }
    biasv[blk] = be1[blk * 16 + n];
  }

  int start = ebs[g], cnt = ecnt[g];
  int lim = start + cnt;
  int ntiles = (cnt + 15) >> 4;
  const int nstream = ESLICE * 4;
  int sid = slice * 4 + wave;
  int tpc = (ntiles + nstream - 1) / nstream;
  int t0 = sid * tpc;
  int t1 = t0 + tpc; if (t1 > ntiles) t1 = ntiles;

  float racc[8] = {0.f, 0.f, 0.f, 0.f, 0.f, 0.f, 0.f, 0.f};

  for (int t = t0; t < t1; ++t) {
    int jb = start + (t << 4);
    int row = jb + n;
    int rc = row < lim - 1 ? row : lim - 1;
    bf16x8 afrag = {};
    if (kg < 2) afrag = *(const bf16x8*)(eaS + (size_t)rc * DE + kg * 8);
    bool full = (jb + 16 <= lim);
    if (full) {
      #pragma unroll
      for (int blk = 0; blk < 8; ++blk) {
        f32x4 acc = {0.f, 0.f, 0.f, 0.f};
        acc = __builtin_amdgcn_mfma_f32_16x16x32_bf16(afrag, bfrag[blk], acc, 0, 0, 0);
        #pragma unroll
        for (int r = 0; r < 4; ++r)
          racc[blk] += fmaxf(acc[r] + biasv[blk], 0.f);
      }
    } else {
      #pragma unroll
      for (int blk = 0; blk < 8; ++blk) {
        f32x4 acc = {0.f, 0.f, 0.f, 0.f};
        acc = __builtin_amdgcn_mfma_f32_16x16x32_bf16(afrag, bfrag[blk], acc, 0, 0, 0);
        #pragma unroll
        for (int r = 0; r < 4; ++r) {
          int rr = kg * 4 + r;
          if (jb + rr < lim) racc[blk] += fmaxf(acc[r] + biasv[blk], 0.f);
        }
      }
    }
  }

  #pragma unroll
  for (int blk = 0; blk < 8; ++blk) {
    float vsum = racc[blk];
    vsum += __shfl_xor(vsum, 16);
    vsum += __shfl_xor(vsum, 32);
    if (lane < 16) atomicAdd(&esum[(size_t)g * 128 + blk * 16 + n], vsum);
  }
}

// ---------------- K10: graph mean + (edge mean hidden) @ We2 + be2 -> out ----------------
__global__ void k_final(const float* __restrict__ esum, const int* __restrict__ ecnt,
                        const float* __restrict__ gsum, const float* __restrict__ gcnt,
                        const float* __restrict__ We2, const float* __restrict__ be2,
                        float* __restrict__ out) {
  __shared__ float mh[128];
  int g = blockIdx.x, c = threadIdx.x;
  int ec = ecnt[g];
  mh[c] = (ec > 0) ? esum[(size_t)g * 128 + c] / (float)ec : 0.f;
  __syncthreads();
  float acc = 0.f;
  #pragma unroll 8
  for (int k = 0; k < 128; ++k) acc += mh[k] * We2[k * 128 + c];
  float er = (ec > 0) ? (acc + be2[c]) : 0.f;
  float gr = gsum[(size_t)g * 128 + c] / fmaxf(gcnt[g], 1.f);
  out[(size_t)g * 128 + c] = gr + er;
}

extern "C" void kernel_launch(void* const* d_in, const int* in_sizes, int n_in,
                              void* d_out, int out_size, void* d_ws, size_t ws_size,
                              hipStream_t stream) {
  const float* x        = (const float*)d_in[0];
  const int*   ei       = (const int*)d_in[1];
  const int*   batch    = (const int*)d_in[2];
  const float* edge_attr= (const float*)d_in[3];
  const float* W1 = (const float*)d_in[5];
  const float* b1 = (const float*)d_in[6];
  const float* g1 = (const float*)d_in[7];
  const float* bt1= (const float*)d_in[8];
  const float* m1 = (const float*)d_in[9];
  const float* v1 = (const float*)d_in[10];
  const float* W2 = (const float*)d_in[11];
  const float* b2 = (const float*)d_in[12];
  const float* g2 = (const float*)d_in[13];
  const float* bt2= (const float*)d_in[14];
  const float* m2 = (const float*)d_in[15];
  const float* v2 = (const float*)d_in[16];
  const float* We1= (const float*)d_in[17];
  const float* be1= (const float*)d_in[18];
  const float* We2= (const float*)d_in[19];
  const float* be2= (const float*)d_in[20];
  float* out = (float*)d_out;

  char* ws = (char*)d_ws;
  size_t off = 0;
  auto take = [&](size_t bytes) -> char* {
    char* p = ws + off;
    off += (bytes + 255) & ~(size_t)255;
    return p;
  };
  __bf16* A       = (__bf16*)take((size_t)N_NODES * 128 * 2);
  float*  B       = (float*) take((size_t)N_NODES * 128 * 4);
  float*  dinv    = (float*) take((size_t)N_NODES * 4);
  int*    deg     = (int*)   take((size_t)N_NODES * 4);
  int*    rs      = (int*)   take((size_t)N_NODES * 4);
  int*    nbr     = (int*)   take((size_t)(N_EDGES + N_NODES) * 4);
  int2*   pairs   = (int2*)  take((size_t)N_EDGES * 8);
  __bf16* eaS     = (__bf16*)take((size_t)N_EDGES * DE * 2);
  __bf16* Wf1     = (__bf16*)take((size_t)16384 * 2);
  __bf16* Wf2     = (__bf16*)take((size_t)16384 * 2);
  int*    ecnt    = (int*)   take((size_t)G * 4);
  int*    ebs     = (int*)   take((size_t)G * 4);
  int*    ecur_pad= (int*)   take((size_t)G * 16 * 4);
  int*    dcnt    = (int*)   take((size_t)NBKT * 4);
  int*    dbs     = (int*)   take((size_t)NBKT * 4);
  int*    dcur_pad= (int*)   take((size_t)NBKT * 16 * 4);
  float*  gcnt    = (float*) take((size_t)G * 4);
  float*  esum    = (float*) take((size_t)G * 128 * 4);
  float*  gsum    = (float*) take((size_t)G * 128 * 4);
  int*    part    = (int*)   take((size_t)NSB * 4);

  k_init<<<(N_NODES + 255) / 256, 256, 0, stream>>>(deg, ecnt, dcnt, gcnt, gsum, esum);
  k_prep_w<<<8, 256, 0, stream>>>(W1, Wf1);
  k_prep_w<<<8, 256, 0, stream>>>(W2, Wf2);
  k_count<<<(N_EDGES + 4095) / 4096, 256, 0, stream>>>(ei, batch, deg, ecnt, dcnt);
  k_scan_part<<<NSB, 256, 0, stream>>>(deg, part);
  k_scan_mid<<<1, 512, 0, stream>>>(part, ecnt, ebs, ecur_pad, dcnt, dbs, dcur_pad);
  k_scan_write<<<NSB, 256, 0, stream>>>(deg, part, rs, dinv);
  k_scatter<<<(N_EDGES + EPB - 1) / EPB, 256, 0, stream>>>(ei, batch, edge_attr, ecur_pad, dcur_pad, pairs, eaS);
  k_scatter_nbr<<<NBKT, 256, 0, stream>>>(pairs, dbs, dcnt, rs, nbr);
  const int aggBlocks = (N_NODES + 4 * AGG_CH - 1) / (4 * AGG_CH);
  // layer 1
  k_gemm_mfma<<<(N_NODES + 63) / 64, 256, 0, stream>>>(x, Wf1, dinv, A);
  k_agg_bn<<<aggBlocks, 256, 0, stream>>>((const unsigned*)A, nbr, rs, deg, dinv, b1, g1, bt1, m1, v1, B);
  // layer 2 (+ pooling fused)
  k_gemm_mfma<<<(N_NODES + 63) / 64, 256, 0, stream>>>(B, Wf2, dinv, A);
  k_agg_bn_pool<<<aggBlocks, 256, 0, stream>>>((const unsigned*)A, nbr, rs, deg, dinv, batch, b2, g2, bt2, m2, v2, gsum, gcnt);
  // edge path
  k_edge_hidden<<<G * ESLICE, 256, 0, stream>>>(eaS, ebs, ecnt, We1, be1, esum);
  k_final<<<G, 128, 0, stream>>>(esum, ecnt, gsum, gcnt, We2, be2, out);
}